// Round 8
// baseline (551.765 us; speedup 1.0000x reference)
//
#include <hip/hip_runtime.h>
#include <math.h>

// ---------------------------------------------------------------------------
// VectorQuantizer3D — R16: (1) partial-minima layout transposed+packed:
// bDD[row][chunk]=(top1,top2) float2 + bI[row][chunk] — resolve's combine
// becomes 2 coalesced reads/row (was 96 scattered 4B reads at 64KB stride,
// cross-XCD, latency-exposed); the scatter moves to argmin's write side.
// (2) se+split_w+ema merged into prep_w (wave=code row -> se shfl reduce
// bit-identical; -2 launches, -8MB W re-reads). (3) scratch re-layout, all
// gload_lds sources 16B-aligned. argmin schedule/numerics unchanged from R15
// (validated absmax 0.0, margins 1.5e-4).
// ---------------------------------------------------------------------------

#define N_E    4096
#define EDIM   256
#define SPAT   8192
#define NROWS  16384
#define ZELEMS 4194304
#define NCHUNK 32        // code chunks of 128
#define NLOSSPARTS 16384

// Output offsets (flat float32 in return order)
#define OFF_LOSS    0
#define OFF_ZQ      1
#define OFF_PERP    4194305
#define OFF_ONEHOT  4194306
#define OFF_IDX     71303170
#define OFF_ZOUT    71319554
#define OFF_EMA     75513858

// Scratch (float indices into out), all bases 16B-aligned, in regions
// rewritten by outputs_kernel AFTER their last scratch read:
//   out_zq region [1, 4194305):         wh [4,524292), wl [524292,1048580)
//   out_z  region [71319554, 75513858): bI [71319556,71843844),
//                                       bDD [71843844,72892420),
//                                       zh [72892420,74989572)
#define SCR_WH_F   4
#define SCR_WL_F   524292
#define SCR_BI_F   71319556
#define SCR_BDD_F  71843844
#define SCR_ZH_F   72892420

// Soundness at 1.5e-4 (2-product): |q_mfma - q_r6| <= 2|dm| + ulp(256);
// dm = sum z_lo*w_hi, sigma ~4.5e-6. Wrong skip/selection needs many-sigma.
// Empirically validated at 1.5e-4 by R10/R11/R14/R15 (absmax 0.0).
#define MARG 1.5e-4f
#define GAPM 1.5e-4f

typedef unsigned short u16;
typedef short short8 __attribute__((ext_vector_type(8)));
typedef float f32x4 __attribute__((ext_vector_type(4)));
typedef const void __attribute__((address_space(1)))* gas1;
typedef void __attribute__((address_space(3)))* las3;
#define GLOAD16(g, l) __builtin_amdgcn_global_load_lds((gas1)(g), (las3)(l), 16, 0, 0)

__device__ __forceinline__ u16 f2bf(float f) {   // RTNE fp32 -> bf16
    unsigned u = __float_as_uint(f);
    return (u16)((u + 0x7fffu + ((u >> 16) & 1u)) >> 16);
}
__device__ __forceinline__ float bf2f(u16 h) {
    return __uint_as_float(((unsigned)h) << 16);
}

// ---------------------------------------------------------------------------
// K0a: prep_w — fused se + split_w + ema (each wave owns one code row).
// se numerics VERBATIM R6 (same float4 read, same shfl_down chain).
// ---------------------------------------------------------------------------
__global__ __launch_bounds__(256) void prep_w_kernel(
        const float* __restrict__ W, const float* __restrict__ ema,
        u16* __restrict__ wh, u16* __restrict__ wl,
        float* __restrict__ se, float* __restrict__ out_ema) {
    const size_t t = (size_t)blockIdx.x * 256 + threadIdx.x;   // 0..262143
    const int code = (int)(t >> 6);
    const int lane = threadIdx.x & 63;

    const float4 v = *(const float4*)(W + t * 4);

    // bf16 hi/lo split
    u16 h0 = f2bf(v.x), h1 = f2bf(v.y), h2 = f2bf(v.z), h3 = f2bf(v.w);
    u16 l0 = f2bf(v.x - bf2f(h0)), l1 = f2bf(v.y - bf2f(h1));
    u16 l2 = f2bf(v.z - bf2f(h2)), l3 = f2bf(v.w - bf2f(h3));
    uint2 hp, lp;
    hp.x = (unsigned)h0 | ((unsigned)h1 << 16); hp.y = (unsigned)h2 | ((unsigned)h3 << 16);
    lp.x = (unsigned)l0 | ((unsigned)l1 << 16); lp.y = (unsigned)l2 | ((unsigned)l3 << 16);
    *(uint2*)(wh + t * 4) = hp;
    *(uint2*)(wl + t * 4) = lp;

    // ema (same per-element expression as the old ema_kernel)
    const float4 e4 = *(const float4*)(ema + t * 4);
    float4 o4;
    o4.x = 0.25f * e4.x + 0.75f * v.x;
    o4.y = 0.25f * e4.y + 0.75f * v.y;
    o4.z = 0.25f * e4.z + 0.75f * v.z;
    o4.w = 0.25f * e4.w + 0.75f * v.w;
    *(float4*)(out_ema + t * 4) = o4;

    // se — VERBATIM R6 numerics
    float s = v.x * v.x + v.y * v.y + v.z * v.z + v.w * v.w;
    #pragma unroll
    for (int off = 32; off > 0; off >>= 1) s += __shfl_down(s, off);
    if (lane == 0) se[code] = s;
}

// ---------------------------------------------------------------------------
// K0b: sz[row] = ||z_row||^2 — R6's exact summation order (untouched).
// ---------------------------------------------------------------------------
__global__ __launch_bounds__(512) void rnorm_kernel(const float* __restrict__ z,
                                                    float* __restrict__ sz) {
    const int r0 = blockIdx.x * 128;
    const int bb = r0 >> 13;
    const int sp0 = r0 & (SPAT - 1);
    const float* zb = z + (size_t)bb * (EDIM * SPAT) + sp0;
    __shared__ float szp[4][128];
    const int lr = threadIdx.x & 127, kq = threadIdx.x >> 7;
    float s = 0.f;
    const float* p = zb + lr + (size_t)(kq * 64) * SPAT;
    for (int k = 0; k < 64; ++k) {
        float v = p[(size_t)k * SPAT];
        s += v * v;
    }
    szp[kq][lr] = s;
    __syncthreads();
    if (threadIdx.x < 128)
        sz[r0 + threadIdx.x] =
            ((szp[0][threadIdx.x] + szp[1][threadIdx.x]) + szp[2][threadIdx.x]) + szp[3][threadIdx.x];
}

// ---------------------------------------------------------------------------
// K0c: z [2][256][8192] -> transposed bf16 hi [16384 rows][256 k].
// ---------------------------------------------------------------------------
__global__ __launch_bounds__(256) void split_z_kernel(const float* __restrict__ z,
                                                      u16* __restrict__ zh) {
    __shared__ float t[128][65];
    const int tid = threadIdx.x, wid = tid >> 6, lane = tid & 63;
    const int sp0 = blockIdx.x * 64, c0 = blockIdx.y * 128, b = blockIdx.z;
    const float* zb = z + (size_t)b * (EDIM * SPAT);
    #pragma unroll
    for (int it = 0; it < 32; ++it) {
        const int cl = wid + 4 * it;                 // 0..127
        t[cl][lane] = zb[(size_t)(c0 + cl) * SPAT + sp0 + lane];
    }
    __syncthreads();
    #pragma unroll
    for (int it = 0; it < 16; ++it) {
        const int r = wid + 4 * it;                  // 0..63
        const float v0 = t[2 * lane][r], v1 = t[2 * lane + 1][r];
        const u16 h0 = f2bf(v0), h1 = f2bf(v1);
        const size_t row = (size_t)b * SPAT + sp0 + r;
        ((unsigned*)zh)[row * 128 + (c0 >> 1) + lane] = (unsigned)h0 | ((unsigned)h1 << 16);
    }
}

// ---------------------------------------------------------------------------
// K1: MFMA argmin + per-chunk top-2 + one-hot zero slice.
// Grid: x = rowblock (128), y = chunk (32). 2-phase pipelined (R15 schedule).
// Output now packed/transposed: bDD[row][chunk]=(d1,d2), bI[row][chunk].
// ---------------------------------------------------------------------------
__global__ __launch_bounds__(256, 3) void argmin_kernel(
        const u16* __restrict__ zh,
        const u16* __restrict__ wh, const u16* __restrict__ wl,
        const float* __restrict__ se, const float* __restrict__ sz,
        float* __restrict__ bDD, int* __restrict__ bI,
        float* __restrict__ out_onehot) {
    __shared__ u16 sW[2][128][64];  // 32 KB: [buf][code][hi32|lo32]
    __shared__ u16 sZ[2][128][32];  // 16 KB: [buf][row ][hi32]
    __shared__ float mD[2][128];
    __shared__ int   mI[2][128];
    __shared__ float mD2[2][128];

    const int tid = threadIdx.x;
    const int wid = tid >> 6, lane = tid & 63;
    const int wm = wid >> 1, wn = wid & 1;
    const int lq = lane >> 4, lr = lane & 15;
    const int chunk = blockIdx.y;          // 0..31
    const int rbase = blockIdx.x * 128;
    const int cbase = chunk * 128;

    // sW staging (validated layout): 1024 16B-chunks/buf, 4/thread.
    const u16* gw[4];
    #pragma unroll
    for (int i = 0; i < 4; ++i) {
        const int o = i * 256 + tid;
        const int row = o >> 3, g = o & 7, u = g ^ (row & 7);
        const int ks = (u & 3) * 8;
        gw[i] = (u < 4 ? wh : wl) + (size_t)(cbase + row) * EDIM + ks;
    }
    // sZ staging: 512 chunks/buf, 2/thread; chunk u at pos g = u ^ ((row>>1)&3).
    const u16* gz[2];
    #pragma unroll
    for (int j = 0; j < 2; ++j) {
        const int o = j * 256 + tid;
        const int row = o >> 2, g = o & 3, u = g ^ ((row >> 1) & 3);
        gz[j] = zh + (size_t)(rbase + row) * EDIM + u * 8;
    }

    char* sWb = (char*)&sW[0][0][0];
    char* sZb = (char*)&sZ[0][0][0];

    // fragment LDS byte offsets within a buffer (stage-invariant)
    int aoff[4][2], boff[4];
    #pragma unroll
    for (int tt = 0; tt < 4; ++tt) {
        const int cl = wn * 64 + tt * 16 + lr;
        const int s0 = lq ^ (cl & 7);
        aoff[tt][0] = cl * 128 + s0 * 16;
        aoff[tt][1] = cl * 128 + (s0 ^ 4) * 16;
        const int rl = wm * 64 + tt * 16 + lr;
        boff[tt] = rl * 64 + (lq ^ ((rl >> 1) & 3)) * 16;
    }

    f32x4 acc[4][4];
    #pragma unroll
    for (int ci = 0; ci < 4; ++ci)
        #pragma unroll
        for (int rj = 0; rj < 4; ++rj) {
            f32x4 zzz = {0.f, 0.f, 0.f, 0.f};
            acc[ci][rj] = zzz;
        }

    #define STAGE(b) do {                                                      \
        _Pragma("unroll")                                                      \
        for (int i = 0; i < 4; ++i) {                                          \
            GLOAD16(gw[i], sWb + (b) * 16384 + (i * 256 + wid * 64) * 16);     \
            gw[i] += 32;                                                       \
        }                                                                      \
        _Pragma("unroll")                                                      \
        for (int j = 0; j < 2; ++j) {                                          \
            GLOAD16(gz[j], sZb + (b) * 8192 + (j * 256 + wid * 64) * 16);      \
            gz[j] += 32;                                                       \
        }                                                                      \
    } while (0)

    STAGE(0);
    __syncthreads();                       // drain prologue -> buf0 ready

    for (int k0 = 0; k0 < 8; ++k0) {
        const int cur = k0 & 1;
        if (k0 < 7) STAGE(cur ^ 1);        // next tile in flight during compute

        const char* wbase = sWb + cur * 16384;
        const char* zbase = sZb + cur * 8192;
        short8 zb[4];
        #pragma unroll
        for (int rj = 0; rj < 4; ++rj)
            zb[rj] = *(const short8*)(zbase + boff[rj]);
        #pragma unroll
        for (int ci = 0; ci < 4; ++ci) {
            const short8 wah = *(const short8*)(wbase + aoff[ci][0]);
            const short8 wal = *(const short8*)(wbase + aoff[ci][1]);
            #pragma unroll
            for (int rj = 0; rj < 4; ++rj) {
                acc[ci][rj] = __builtin_amdgcn_mfma_f32_16x16x32_bf16(wah, zb[rj], acc[ci][rj], 0, 0, 0);
                acc[ci][rj] = __builtin_amdgcn_mfma_f32_16x16x32_bf16(wal, zb[rj], acc[ci][rj], 0, 0, 0);
            }
        }
        __syncthreads();                   // drains next-tile loads + read fence
    }
    #undef STAGE

    // ---- epilogue: per-chunk quantized top-2 (value-only second) ----
    f32x4 sev[4];
    #pragma unroll
    for (int ci = 0; ci < 4; ++ci)
        sev[ci] = *(const f32x4*)(se + cbase + wn * 64 + ci * 16 + lq * 4);

    #pragma unroll
    for (int rj = 0; rj < 4; ++rj) {
        const int rloc = wm * 64 + rj * 16 + lr;
        const float szr = sz[rbase + rloc];
        float b1 = 3.4e38f, b2 = 3.4e38f; int bi1 = 0x7fffffff;
        #pragma unroll
        for (int ci = 0; ci < 4; ++ci) {
            #pragma unroll
            for (int r = 0; r < 4; ++r) {
                const float q = (szr + sev[ci][r]) - 2.0f * acc[ci][rj][r];
                const int code = cbase + wn * 64 + ci * 16 + lq * 4 + r;
                if (q < b1 || (q == b1 && code < bi1)) {
                    b2 = b1; b1 = q; bi1 = code;
                } else if (q < b2) {
                    b2 = q;
                }
            }
        }
        #pragma unroll
        for (int mask = 16; mask <= 32; mask <<= 1) {
            const float od1 = __shfl_xor(b1, mask);
            const int   oi1 = __shfl_xor(bi1, mask);
            const float od2 = __shfl_xor(b2, mask);
            const bool ot = (od1 < b1) || (od1 == b1 && oi1 < bi1);
            if (ot) { b2 = fminf(b1, od2); b1 = od1; bi1 = oi1; }
            else    { b2 = fminf(b2, od1); }
        }
        if (lq == 0) {
            mD[wn][rloc]  = b1;
            mI[wn][rloc]  = bi1;
            mD2[wn][rloc] = b2;
        }
    }
    __syncthreads();
    if (tid < 128) {
        const float d0 = mD[0][tid], d1 = mD[1][tid];
        const int   i0 = mI[0][tid], i1 = mI[1][tid];
        const float s0 = mD2[0][tid], s1 = mD2[1][tid];
        float dm, sm; int im;
        if (d1 < d0 || (d1 == d0 && i1 < i0)) { dm = d1; im = i1; sm = fminf(s1, d0); }
        else                                  { dm = d0; im = i0; sm = fminf(s0, d1); }
        const int row = rbase + tid;
        float2 p; p.x = dm; p.y = sm;
        *(float2*)(bDD + (size_t)row * 64 + chunk * 2) = p;   // scatter-write side
        bI[(size_t)row * 32 + chunk] = im;
    }

    // ---- one-hot zero slice (64 KB per block; drains under block exit) ----
    {
        const int slice = blockIdx.x * 32 + blockIdx.y;   // 0..4095, bijective
        float* oh = out_onehot + (size_t)slice * 16384;
        const float4 z4 = {0.f, 0.f, 0.f, 0.f};
        #pragma unroll
        for (int it = 0; it < 16; ++it)
            *(float4*)(oh + it * 1024 + tid * 4) = z4;
    }
}

// ---------------------------------------------------------------------------
// K1b: resolve — block per row. Combine now reads 2 coalesced runs per row
// (bDD 256B float2, bI 128B). Fast path (gap > GAPM): accept MFMA winner.
// Slow path: R10's validated exact serial-k rescan of candidate chunks.
// ---------------------------------------------------------------------------
__global__ __launch_bounds__(256) void resolve_kernel(
        const float* __restrict__ z, const float* __restrict__ W,
        const float* __restrict__ se, const float* __restrict__ sz,
        const float* __restrict__ bDD, const int* __restrict__ bI,
        int* __restrict__ idx_ws, float* __restrict__ out_idx,
        float* __restrict__ out_onehot) {
    __shared__ float zr[EDIM];
    __shared__ float rd[128];
    __shared__ int   ri[128];
    __shared__ unsigned smask;
    __shared__ int swin, sskip;
    const int row = blockIdx.x;
    const int tid = threadIdx.x;

    if (tid < 64) {
        const int c = tid & 31;
        const float2 dd = *(const float2*)(bDD + (size_t)row * 64 + c * 2);
        const int    i1 = bI[(size_t)row * 32 + c];
        const float d1 = dd.x;
        float b1 = dd.x, b2 = dd.y; int j1 = i1;
        #pragma unroll
        for (int mask = 16; mask > 0; mask >>= 1) {
            const float od1 = __shfl_xor(b1, mask);
            const int   oj1 = __shfl_xor(j1, mask);
            const float od2 = __shfl_xor(b2, mask);
            const bool ot = (od1 < b1) || (od1 == b1 && oj1 < j1);
            if (ot) { b2 = fminf(b1, od2); b1 = od1; j1 = oj1; }
            else    { b2 = fminf(b2, od1); }
        }
        const unsigned long long m = __ballot(d1 <= b1 + MARG);
        if (tid == 0) {
            smask = (unsigned)(m & 0xffffffffu);
            swin  = j1;
            sskip = (b2 - b1 > GAPM) ? 1 : 0;
        }
    }
    __syncthreads();

    if (sskip) {
        if (tid == 0) {
            idx_ws[row]  = swin;
            out_idx[row] = (float)swin;
            out_onehot[(size_t)row * N_E + swin] = 1.0f;
        }
        return;
    }

    // slow path: exact rescan (R10-validated numerics, unchanged)
    {
        const int b = row >> 13, sp = row & (SPAT - 1);
        zr[tid] = z[(size_t)b * (EDIM * SPAT) + (size_t)tid * SPAT + sp];
    }
    __syncthreads();

    const float szr = sz[row];
    unsigned cmask = smask;
    float best = 3.4e38f; int bi = 0x7fffffff;
    while (cmask) {
        const int cc = __ffs(cmask) - 1;
        cmask &= cmask - 1;
        if (tid < 128) {
            const int code = cc * 128 + tid;
            const float* wr = W + (size_t)code * EDIM;
            float s = 0.f;
            for (int k = 0; k < EDIM; ++k) s += zr[k] * wr[k];   // serial k
            const float q = (szr + se[code]) - 2.0f * s;
            if (q < best || (q == best && code < bi)) { best = q; bi = code; }
        }
    }
    if (tid < 128) { rd[tid] = best; ri[tid] = bi; }
    __syncthreads();
    for (int off = 64; off > 0; off >>= 1) {
        if (tid < off) {
            const float od = rd[tid + off]; const int oi = ri[tid + off];
            if (od < rd[tid] || (od == rd[tid] && oi < ri[tid])) {
                rd[tid] = od; ri[tid] = oi;
            }
        }
        __syncthreads();
    }
    if (tid == 0) {
        const int ii = ri[0];
        idx_ws[row]  = ii;
        out_idx[row] = (float)ii;
        out_onehot[(size_t)row * N_E + ii] = 1.0f;
    }
}

// ---------------------------------------------------------------------------
// K2: z_q_out, z_out, loss partials — unchanged from R6.
// ---------------------------------------------------------------------------
__global__ __launch_bounds__(256) void outputs_kernel(
        const float* __restrict__ z, const float* __restrict__ W,
        const int* __restrict__ idx,
        float* __restrict__ zq_out, float* __restrict__ z_out,
        double* __restrict__ loss_parts) {
    const int t  = blockIdx.x * 256 + threadIdx.x;
    const float zv = z[t];
    const int sp = t & (SPAT - 1);
    const int c  = (t >> 13) & 255;
    const int b  = t >> 21;
    const int n  = (b << 13) + sp;
    const int id = idx[n];
    const float e    = W[id * EDIM + c];
    const float diff = e - zv;
    zq_out[t] = zv + diff;
    z_out[t]  = zv;

    double ds = (double)(diff * diff);
    #pragma unroll
    for (int off = 32; off > 0; off >>= 1) ds += __shfl_down(ds, off);
    __shared__ double bsum[4];
    const int lane = threadIdx.x & 63, w = threadIdx.x >> 6;
    if (lane == 0) bsum[w] = ds;
    __syncthreads();
    if (threadIdx.x == 0)
        loss_parts[blockIdx.x] = bsum[0] + bsum[1] + bsum[2] + bsum[3];
}

// ---------------------------------------------------------------------------
// K4: histogram + perplexity + loss finalize — unchanged.
// ---------------------------------------------------------------------------
__global__ __launch_bounds__(1024) void final_kernel(
        const int* __restrict__ idx, const double* __restrict__ loss_parts,
        float* __restrict__ out_loss, float* __restrict__ out_perp) {
    __shared__ int   hist[N_E];
    __shared__ float ps[1024];
    __shared__ double ls[1024];
    const int tid = threadIdx.x;

    for (int i = tid; i < N_E; i += 1024) hist[i] = 0;
    __syncthreads();
    for (int r = tid; r < NROWS; r += 1024) atomicAdd(&hist[idx[r]], 1);
    __syncthreads();

    float s = 0.f;
    for (int c = tid; c < N_E; c += 1024) {
        const float p = (float)hist[c] * (1.0f / (float)NROWS);
        s += p * logf(p + 1e-10f);
    }
    double l = 0.0;
    for (int c = tid; c < NLOSSPARTS; c += 1024) l += loss_parts[c];
    ps[tid] = s;
    ls[tid] = l;
    __syncthreads();
    for (int off = 512; off > 0; off >>= 1) {
        if (tid < off) {
            ps[tid] += ps[tid + off];
            ls[tid] += ls[tid + off];
        }
        __syncthreads();
    }
    if (tid == 0) {
        *out_perp = expf(-ps[0]);
        const float m = (float)(ls[0] / (double)ZELEMS);
        *out_loss = m + 0.25f * m;
    }
}

// ---------------------------------------------------------------------------
extern "C" void kernel_launch(void* const* d_in, const int* in_sizes, int n_in,
                              void* d_out, int out_size, void* d_ws, size_t ws_size,
                              hipStream_t stream) {
    const float* z   = (const float*)d_in[0];
    const float* W   = (const float*)d_in[1];
    const float* ema = (const float*)d_in[2];
    float* out = (float*)d_out;

    float* out_loss   = out + OFF_LOSS;
    float* out_zq     = out + OFF_ZQ;
    float* out_perp   = out + OFF_PERP;
    float* out_onehot = out + OFF_ONEHOT;
    float* out_idx    = out + OFF_IDX;
    float* out_z      = out + OFF_ZOUT;
    float* out_ema    = out + OFF_EMA;

    // scratch inside later-overwritten output regions (16B-aligned bases)
    u16*   wh  = (u16*)(out + SCR_WH_F);
    u16*   wl  = (u16*)(out + SCR_WL_F);
    int*   bI  = (int*)(out + SCR_BI_F);
    float* bDD = out + SCR_BDD_F;
    u16*   zh  = (u16*)(out + SCR_ZH_F);

    // workspace
    char* ws = (char*)d_ws;
    float*  se    = (float*)ws;                   // 16 KB
    float*  sz    = (float*)(ws + 16384);         // 64 KB
    int*    idxb  = (int*)  (ws + 81920);         // 64 KB
    double* lossp = (double*)(ws + 147456);       // 128 KB

    prep_w_kernel<<<1024, 256, 0, stream>>>(W, ema, wh, wl, se, out_ema);
    rnorm_kernel<<<128, 512, 0, stream>>>(z, sz);
    split_z_kernel<<<dim3(128, 2, 2), 256, 0, stream>>>(z, zh);
    argmin_kernel<<<dim3(NROWS / 128, NCHUNK), 256, 0, stream>>>(
        zh, wh, wl, se, sz, bDD, bI, out_onehot);
    resolve_kernel<<<NROWS, 256, 0, stream>>>(z, W, se, sz, bDD, bI,
                                              idxb, out_idx, out_onehot);
    outputs_kernel<<<ZELEMS / 256, 256, 0, stream>>>(z, W, idxb, out_zq, out_z,
                                                     lossp);
    final_kernel<<<1, 1024, 0, stream>>>(idxb, lossp, out_loss, out_perp);
}

// Round 9
// 550.540 us; speedup vs baseline: 1.0022x; 1.0022x over previous
//
#include <hip/hip_runtime.h>
#include <math.h>

// ---------------------------------------------------------------------------
// VectorQuantizer3D — R17: kill the serial histogram tail. Evidence: R6-era
// comment (global atomics on idx serialized ~200us due to data-dependent code
// concentration) => final_kernel's single-block 16384 LDS atomicAdds are a
// ~40-65us serial tail on one CU (invisible under the 200us harness fills).
// (1) hist_kernel: 16 blocks x 1024 rows, private LDS hist, merge via global
//     atomics on 4096 distinct addresses; ghist zeroed in prep_all.
//     final_kernel reads ghist with the identical c-mapping/order ->
//     bit-identical loss/perplexity.
// (2) prep_w + split_z + rnorm fused into prep_all (blockIdx-range dispatch;
//     rnorm re-expressed at 256 threads with identical szp partials/order).
// (3) resolve downsized to 128 threads (half was idle).
// argmin/outputs/margins/layouts unchanged from R16 (absmax 0.0 validated).
// ---------------------------------------------------------------------------

#define N_E    4096
#define EDIM   256
#define SPAT   8192
#define NROWS  16384
#define ZELEMS 4194304
#define NCHUNK 32        // code chunks of 128
#define NLOSSPARTS 16384

// Output offsets (flat float32 in return order)
#define OFF_LOSS    0
#define OFF_ZQ      1
#define OFF_PERP    4194305
#define OFF_ONEHOT  4194306
#define OFF_IDX     71303170
#define OFF_ZOUT    71319554
#define OFF_EMA     75513858

// Scratch (float indices into out), all bases 16B-aligned, in regions
// rewritten by outputs_kernel AFTER their last scratch read:
//   out_zq region [1, 4194305):         wh [4,524292), wl [524292,1048580)
//   out_z  region [71319554, 75513858): bI [71319556,71843844),
//                                       bDD [71843844,72892420),
//                                       zh [72892420,74989572)
#define SCR_WH_F   4
#define SCR_WL_F   524292
#define SCR_BI_F   71319556
#define SCR_BDD_F  71843844
#define SCR_ZH_F   72892420

// Soundness at 1.5e-4 (2-product): |q_mfma - q_r6| <= 2|dm| + ulp(256);
// dm = sum z_lo*w_hi, sigma ~2.5e-6. Wrong skip/selection needs many-sigma.
// Empirically validated at 1.5e-4 by R10/R11/R14/R15/R16 (absmax 0.0).
#define MARG 1.5e-4f
#define GAPM 1.5e-4f

// prep_all blockIdx ranges
#define PB_W0   0        // 1024 blocks: W split + ema + se
#define PB_Z0   1024     // 512 blocks: split_z
#define PB_N0   1536     // 128 blocks: rnorm
#define PB_H0   1664     // 4 blocks: ghist zero
#define PB_TOT  1668

typedef unsigned short u16;
typedef short short8 __attribute__((ext_vector_type(8)));
typedef float f32x4 __attribute__((ext_vector_type(4)));
typedef const void __attribute__((address_space(1)))* gas1;
typedef void __attribute__((address_space(3)))* las3;
#define GLOAD16(g, l) __builtin_amdgcn_global_load_lds((gas1)(g), (las3)(l), 16, 0, 0)

__device__ __forceinline__ u16 f2bf(float f) {   // RTNE fp32 -> bf16
    unsigned u = __float_as_uint(f);
    return (u16)((u + 0x7fffu + ((u >> 16) & 1u)) >> 16);
}
__device__ __forceinline__ float bf2f(u16 h) {
    return __uint_as_float(((unsigned)h) << 16);
}

// ---------------------------------------------------------------------------
// K0: prep_all — fused {W split + ema + se} | split_z | rnorm | ghist zero.
// Each block takes exactly one branch (no cross-branch barriers).
// ---------------------------------------------------------------------------
__global__ __launch_bounds__(256) void prep_all_kernel(
        const float* __restrict__ W, const float* __restrict__ ema,
        const float* __restrict__ z,
        u16* __restrict__ wh, u16* __restrict__ wl,
        float* __restrict__ se, float* __restrict__ out_ema,
        u16* __restrict__ zh, float* __restrict__ sz,
        int* __restrict__ ghist) {
    __shared__ float t[128][65];       // split_z transpose tile
    __shared__ float szp[4][128];      // rnorm partials
    const int bx  = blockIdx.x;
    const int tid = threadIdx.x;

    if (bx < PB_Z0) {
        // ---- W prep: split + ema + se (VERBATIM R6 se numerics) ----
        const size_t tt = (size_t)bx * 256 + tid;       // 0..262143
        const int code = (int)(tt >> 6);
        const int lane = tid & 63;
        const float4 v = *(const float4*)(W + tt * 4);

        u16 h0 = f2bf(v.x), h1 = f2bf(v.y), h2 = f2bf(v.z), h3 = f2bf(v.w);
        u16 l0 = f2bf(v.x - bf2f(h0)), l1 = f2bf(v.y - bf2f(h1));
        u16 l2 = f2bf(v.z - bf2f(h2)), l3 = f2bf(v.w - bf2f(h3));
        uint2 hp, lp;
        hp.x = (unsigned)h0 | ((unsigned)h1 << 16); hp.y = (unsigned)h2 | ((unsigned)h3 << 16);
        lp.x = (unsigned)l0 | ((unsigned)l1 << 16); lp.y = (unsigned)l2 | ((unsigned)l3 << 16);
        *(uint2*)(wh + tt * 4) = hp;
        *(uint2*)(wl + tt * 4) = lp;

        const float4 e4 = *(const float4*)(ema + tt * 4);
        float4 o4;
        o4.x = 0.25f * e4.x + 0.75f * v.x;
        o4.y = 0.25f * e4.y + 0.75f * v.y;
        o4.z = 0.25f * e4.z + 0.75f * v.z;
        o4.w = 0.25f * e4.w + 0.75f * v.w;
        *(float4*)(out_ema + tt * 4) = o4;

        float s = v.x * v.x + v.y * v.y + v.z * v.z + v.w * v.w;
        #pragma unroll
        for (int off = 32; off > 0; off >>= 1) s += __shfl_down(s, off);
        if (lane == 0) se[code] = s;
    } else if (bx < PB_N0) {
        // ---- split_z: transposed bf16 hi [16384 rows][256 k] ----
        const int sub = bx - PB_Z0;
        const int sp0 = (sub & 127) * 64, c0 = ((sub >> 7) & 1) * 128, b = sub >> 8;
        const int wid = tid >> 6, lane = tid & 63;
        const float* zb = z + (size_t)b * (EDIM * SPAT);
        #pragma unroll
        for (int it = 0; it < 32; ++it) {
            const int cl = wid + 4 * it;                 // 0..127
            t[cl][lane] = zb[(size_t)(c0 + cl) * SPAT + sp0 + lane];
        }
        __syncthreads();
        #pragma unroll
        for (int it = 0; it < 16; ++it) {
            const int r = wid + 4 * it;                  // 0..63
            const float v0 = t[2 * lane][r], v1 = t[2 * lane + 1][r];
            const u16 h0 = f2bf(v0), h1 = f2bf(v1);
            const size_t row = (size_t)b * SPAT + sp0 + r;
            ((unsigned*)zh)[row * 128 + (c0 >> 1) + lane] = (unsigned)h0 | ((unsigned)h1 << 16);
        }
    } else if (bx < PB_H0) {
        // ---- rnorm (R6 exact order; 256-thread variant, identical partials)
        const int r0 = (bx - PB_N0) * 128;
        const int bb = r0 >> 13;
        const int sp0 = r0 & (SPAT - 1);
        const float* zb = z + (size_t)bb * (EDIM * SPAT) + sp0;
        const int lr = tid & 127, kh = tid >> 7;         // kh 0..1
        #pragma unroll
        for (int h = 0; h < 2; ++h) {
            const int kq = kh * 2 + h;                   // covers 0..3
            float s = 0.f;
            const float* p = zb + lr + (size_t)(kq * 64) * SPAT;
            for (int k = 0; k < 64; ++k) {
                float v = p[(size_t)k * SPAT];
                s += v * v;
            }
            szp[kq][lr] = s;
        }
        __syncthreads();
        if (tid < 128)
            sz[r0 + tid] = ((szp[0][tid] + szp[1][tid]) + szp[2][tid]) + szp[3][tid];
    } else {
        // ---- ghist zero: 4 blocks x 1024 entries ----
        const int base = (bx - PB_H0) * 1024;
        #pragma unroll
        for (int j = 0; j < 4; ++j) ghist[base + j * 256 + tid] = 0;
    }
}

// ---------------------------------------------------------------------------
// K1: MFMA argmin + per-chunk top-2 + one-hot zero slice (unchanged R16).
// ---------------------------------------------------------------------------
__global__ __launch_bounds__(256, 3) void argmin_kernel(
        const u16* __restrict__ zh,
        const u16* __restrict__ wh, const u16* __restrict__ wl,
        const float* __restrict__ se, const float* __restrict__ sz,
        float* __restrict__ bDD, int* __restrict__ bI,
        float* __restrict__ out_onehot) {
    __shared__ u16 sW[2][128][64];  // 32 KB: [buf][code][hi32|lo32]
    __shared__ u16 sZ[2][128][32];  // 16 KB: [buf][row ][hi32]
    __shared__ float mD[2][128];
    __shared__ int   mI[2][128];
    __shared__ float mD2[2][128];

    const int tid = threadIdx.x;
    const int wid = tid >> 6, lane = tid & 63;
    const int wm = wid >> 1, wn = wid & 1;
    const int lq = lane >> 4, lr = lane & 15;
    const int chunk = blockIdx.y;          // 0..31
    const int rbase = blockIdx.x * 128;
    const int cbase = chunk * 128;

    const u16* gw[4];
    #pragma unroll
    for (int i = 0; i < 4; ++i) {
        const int o = i * 256 + tid;
        const int row = o >> 3, g = o & 7, u = g ^ (row & 7);
        const int ks = (u & 3) * 8;
        gw[i] = (u < 4 ? wh : wl) + (size_t)(cbase + row) * EDIM + ks;
    }
    const u16* gz[2];
    #pragma unroll
    for (int j = 0; j < 2; ++j) {
        const int o = j * 256 + tid;
        const int row = o >> 2, g = o & 3, u = g ^ ((row >> 1) & 3);
        gz[j] = zh + (size_t)(rbase + row) * EDIM + u * 8;
    }

    char* sWb = (char*)&sW[0][0][0];
    char* sZb = (char*)&sZ[0][0][0];

    int aoff[4][2], boff[4];
    #pragma unroll
    for (int tt = 0; tt < 4; ++tt) {
        const int cl = wn * 64 + tt * 16 + lr;
        const int s0 = lq ^ (cl & 7);
        aoff[tt][0] = cl * 128 + s0 * 16;
        aoff[tt][1] = cl * 128 + (s0 ^ 4) * 16;
        const int rl = wm * 64 + tt * 16 + lr;
        boff[tt] = rl * 64 + (lq ^ ((rl >> 1) & 3)) * 16;
    }

    f32x4 acc[4][4];
    #pragma unroll
    for (int ci = 0; ci < 4; ++ci)
        #pragma unroll
        for (int rj = 0; rj < 4; ++rj) {
            f32x4 zzz = {0.f, 0.f, 0.f, 0.f};
            acc[ci][rj] = zzz;
        }

    #define STAGE(b) do {                                                      \
        _Pragma("unroll")                                                      \
        for (int i = 0; i < 4; ++i) {                                          \
            GLOAD16(gw[i], sWb + (b) * 16384 + (i * 256 + wid * 64) * 16);     \
            gw[i] += 32;                                                       \
        }                                                                      \
        _Pragma("unroll")                                                      \
        for (int j = 0; j < 2; ++j) {                                          \
            GLOAD16(gz[j], sZb + (b) * 8192 + (j * 256 + wid * 64) * 16);      \
            gz[j] += 32;                                                       \
        }                                                                      \
    } while (0)

    STAGE(0);
    __syncthreads();

    for (int k0 = 0; k0 < 8; ++k0) {
        const int cur = k0 & 1;
        if (k0 < 7) STAGE(cur ^ 1);

        const char* wbase = sWb + cur * 16384;
        const char* zbase = sZb + cur * 8192;
        short8 zb[4];
        #pragma unroll
        for (int rj = 0; rj < 4; ++rj)
            zb[rj] = *(const short8*)(zbase + boff[rj]);
        #pragma unroll
        for (int ci = 0; ci < 4; ++ci) {
            const short8 wah = *(const short8*)(wbase + aoff[ci][0]);
            const short8 wal = *(const short8*)(wbase + aoff[ci][1]);
            #pragma unroll
            for (int rj = 0; rj < 4; ++rj) {
                acc[ci][rj] = __builtin_amdgcn_mfma_f32_16x16x32_bf16(wah, zb[rj], acc[ci][rj], 0, 0, 0);
                acc[ci][rj] = __builtin_amdgcn_mfma_f32_16x16x32_bf16(wal, zb[rj], acc[ci][rj], 0, 0, 0);
            }
        }
        __syncthreads();
    }
    #undef STAGE

    f32x4 sev[4];
    #pragma unroll
    for (int ci = 0; ci < 4; ++ci)
        sev[ci] = *(const f32x4*)(se + cbase + wn * 64 + ci * 16 + lq * 4);

    #pragma unroll
    for (int rj = 0; rj < 4; ++rj) {
        const int rloc = wm * 64 + rj * 16 + lr;
        const float szr = sz[rbase + rloc];
        float b1 = 3.4e38f, b2 = 3.4e38f; int bi1 = 0x7fffffff;
        #pragma unroll
        for (int ci = 0; ci < 4; ++ci) {
            #pragma unroll
            for (int r = 0; r < 4; ++r) {
                const float q = (szr + sev[ci][r]) - 2.0f * acc[ci][rj][r];
                const int code = cbase + wn * 64 + ci * 16 + lq * 4 + r;
                if (q < b1 || (q == b1 && code < bi1)) {
                    b2 = b1; b1 = q; bi1 = code;
                } else if (q < b2) {
                    b2 = q;
                }
            }
        }
        #pragma unroll
        for (int mask = 16; mask <= 32; mask <<= 1) {
            const float od1 = __shfl_xor(b1, mask);
            const int   oi1 = __shfl_xor(bi1, mask);
            const float od2 = __shfl_xor(b2, mask);
            const bool ot = (od1 < b1) || (od1 == b1 && oi1 < bi1);
            if (ot) { b2 = fminf(b1, od2); b1 = od1; bi1 = oi1; }
            else    { b2 = fminf(b2, od1); }
        }
        if (lq == 0) {
            mD[wn][rloc]  = b1;
            mI[wn][rloc]  = bi1;
            mD2[wn][rloc] = b2;
        }
    }
    __syncthreads();
    if (tid < 128) {
        const float d0 = mD[0][tid], d1 = mD[1][tid];
        const int   i0 = mI[0][tid], i1 = mI[1][tid];
        const float s0 = mD2[0][tid], s1 = mD2[1][tid];
        float dm, sm; int im;
        if (d1 < d0 || (d1 == d0 && i1 < i0)) { dm = d1; im = i1; sm = fminf(s1, d0); }
        else                                  { dm = d0; im = i0; sm = fminf(s0, d1); }
        const int row = rbase + tid;
        float2 p; p.x = dm; p.y = sm;
        *(float2*)(bDD + (size_t)row * 64 + chunk * 2) = p;
        bI[(size_t)row * 32 + chunk] = im;
    }

    {
        const int slice = blockIdx.x * 32 + blockIdx.y;   // 0..4095, bijective
        float* oh = out_onehot + (size_t)slice * 16384;
        const float4 z4 = {0.f, 0.f, 0.f, 0.f};
        #pragma unroll
        for (int it = 0; it < 16; ++it)
            *(float4*)(oh + it * 1024 + tid * 4) = z4;
    }
}

// ---------------------------------------------------------------------------
// K1b: resolve — 128 threads/block (was 256 with half idle). Same numerics.
// ---------------------------------------------------------------------------
__global__ __launch_bounds__(128) void resolve_kernel(
        const float* __restrict__ z, const float* __restrict__ W,
        const float* __restrict__ se, const float* __restrict__ sz,
        const float* __restrict__ bDD, const int* __restrict__ bI,
        int* __restrict__ idx_ws, float* __restrict__ out_idx,
        float* __restrict__ out_onehot) {
    __shared__ float zr[EDIM];
    __shared__ float rd[128];
    __shared__ int   ri[128];
    __shared__ unsigned smask;
    __shared__ int swin, sskip;
    const int row = blockIdx.x;
    const int tid = threadIdx.x;

    if (tid < 64) {
        const int c = tid & 31;
        const float2 dd = *(const float2*)(bDD + (size_t)row * 64 + c * 2);
        const int    i1 = bI[(size_t)row * 32 + c];
        const float d1 = dd.x;
        float b1 = dd.x, b2 = dd.y; int j1 = i1;
        #pragma unroll
        for (int mask = 16; mask > 0; mask >>= 1) {
            const float od1 = __shfl_xor(b1, mask);
            const int   oj1 = __shfl_xor(j1, mask);
            const float od2 = __shfl_xor(b2, mask);
            const bool ot = (od1 < b1) || (od1 == b1 && oj1 < j1);
            if (ot) { b2 = fminf(b1, od2); b1 = od1; j1 = oj1; }
            else    { b2 = fminf(b2, od1); }
        }
        const unsigned long long m = __ballot(d1 <= b1 + MARG);
        if (tid == 0) {
            smask = (unsigned)(m & 0xffffffffu);
            swin  = j1;
            sskip = (b2 - b1 > GAPM) ? 1 : 0;
        }
    }
    __syncthreads();

    if (sskip) {
        if (tid == 0) {
            idx_ws[row]  = swin;
            out_idx[row] = (float)swin;
            out_onehot[(size_t)row * N_E + swin] = 1.0f;
        }
        return;
    }

    // slow path: exact rescan (R10-validated numerics, unchanged)
    {
        const int b = row >> 13, sp = row & (SPAT - 1);
        zr[tid]       = z[(size_t)b * (EDIM * SPAT) + (size_t)tid * SPAT + sp];
        zr[tid + 128] = z[(size_t)b * (EDIM * SPAT) + (size_t)(tid + 128) * SPAT + sp];
    }
    __syncthreads();

    const float szr = sz[row];
    unsigned cmask = smask;
    float best = 3.4e38f; int bi = 0x7fffffff;
    while (cmask) {
        const int cc = __ffs(cmask) - 1;
        cmask &= cmask - 1;
        const int code = cc * 128 + tid;
        const float* wr = W + (size_t)code * EDIM;
        float s = 0.f;
        for (int k = 0; k < EDIM; ++k) s += zr[k] * wr[k];   // serial k
        const float q = (szr + se[code]) - 2.0f * s;
        if (q < best || (q == best && code < bi)) { best = q; bi = code; }
    }
    rd[tid] = best; ri[tid] = bi;
    __syncthreads();
    for (int off = 64; off > 0; off >>= 1) {
        if (tid < off) {
            const float od = rd[tid + off]; const int oi = ri[tid + off];
            if (od < rd[tid] || (od == rd[tid] && oi < ri[tid])) {
                rd[tid] = od; ri[tid] = oi;
            }
        }
        __syncthreads();
    }
    if (tid == 0) {
        const int ii = ri[0];
        idx_ws[row]  = ii;
        out_idx[row] = (float)ii;
        out_onehot[(size_t)row * N_E + ii] = 1.0f;
    }
}

// ---------------------------------------------------------------------------
// K1c: hist — 16 blocks x 1024 rows: private LDS histogram (concentration
// cost parallelized 16x) + merge via global atomics on distinct addresses.
// ---------------------------------------------------------------------------
__global__ __launch_bounds__(1024) void hist_kernel(const int* __restrict__ idx,
                                                    int* __restrict__ ghist) {
    __shared__ int lh[N_E];
    const int tid = threadIdx.x;
    for (int i = tid; i < N_E; i += 1024) lh[i] = 0;
    __syncthreads();
    atomicAdd(&lh[idx[blockIdx.x * 1024 + tid]], 1);
    __syncthreads();
    for (int c = tid; c < N_E; c += 1024) {
        const int v = lh[c];
        if (v) atomicAdd(&ghist[c], v);
    }
}

// ---------------------------------------------------------------------------
// K2: z_q_out, z_out, loss partials — unchanged from R6.
// ---------------------------------------------------------------------------
__global__ __launch_bounds__(256) void outputs_kernel(
        const float* __restrict__ z, const float* __restrict__ W,
        const int* __restrict__ idx,
        float* __restrict__ zq_out, float* __restrict__ z_out,
        double* __restrict__ loss_parts) {
    const int t  = blockIdx.x * 256 + threadIdx.x;
    const float zv = z[t];
    const int sp = t & (SPAT - 1);
    const int c  = (t >> 13) & 255;
    const int b  = t >> 21;
    const int n  = (b << 13) + sp;
    const int id = idx[n];
    const float e    = W[id * EDIM + c];
    const float diff = e - zv;
    zq_out[t] = zv + diff;
    z_out[t]  = zv;

    double ds = (double)(diff * diff);
    #pragma unroll
    for (int off = 32; off > 0; off >>= 1) ds += __shfl_down(ds, off);
    __shared__ double bsum[4];
    const int lane = threadIdx.x & 63, w = threadIdx.x >> 6;
    if (lane == 0) bsum[w] = ds;
    __syncthreads();
    if (threadIdx.x == 0)
        loss_parts[blockIdx.x] = bsum[0] + bsum[1] + bsum[2] + bsum[3];
}

// ---------------------------------------------------------------------------
// K4: perplexity (from ghist, identical c-mapping/order) + loss finalize.
// ---------------------------------------------------------------------------
__global__ __launch_bounds__(1024) void final_kernel(
        const int* __restrict__ ghist, const double* __restrict__ loss_parts,
        float* __restrict__ out_loss, float* __restrict__ out_perp) {
    __shared__ float ps[1024];
    __shared__ double ls[1024];
    const int tid = threadIdx.x;

    float s = 0.f;
    for (int c = tid; c < N_E; c += 1024) {
        const float p = (float)ghist[c] * (1.0f / (float)NROWS);
        s += p * logf(p + 1e-10f);
    }
    double l = 0.0;
    for (int c = tid; c < NLOSSPARTS; c += 1024) l += loss_parts[c];
    ps[tid] = s;
    ls[tid] = l;
    __syncthreads();
    for (int off = 512; off > 0; off >>= 1) {
        if (tid < off) {
            ps[tid] += ps[tid + off];
            ls[tid] += ls[tid + off];
        }
        __syncthreads();
    }
    if (tid == 0) {
        *out_perp = expf(-ps[0]);
        const float m = (float)(ls[0] / (double)ZELEMS);
        *out_loss = m + 0.25f * m;
    }
}

// ---------------------------------------------------------------------------
extern "C" void kernel_launch(void* const* d_in, const int* in_sizes, int n_in,
                              void* d_out, int out_size, void* d_ws, size_t ws_size,
                              hipStream_t stream) {
    const float* z   = (const float*)d_in[0];
    const float* W   = (const float*)d_in[1];
    const float* ema = (const float*)d_in[2];
    float* out = (float*)d_out;

    float* out_loss   = out + OFF_LOSS;
    float* out_zq     = out + OFF_ZQ;
    float* out_perp   = out + OFF_PERP;
    float* out_onehot = out + OFF_ONEHOT;
    float* out_idx    = out + OFF_IDX;
    float* out_z      = out + OFF_ZOUT;
    float* out_ema    = out + OFF_EMA;

    // scratch inside later-overwritten output regions (16B-aligned bases)
    u16*   wh  = (u16*)(out + SCR_WH_F);
    u16*   wl  = (u16*)(out + SCR_WL_F);
    int*   bI  = (int*)(out + SCR_BI_F);
    float* bDD = out + SCR_BDD_F;
    u16*   zh  = (u16*)(out + SCR_ZH_F);

    // workspace
    char* ws = (char*)d_ws;
    float*  se    = (float*)ws;                   // 16 KB
    float*  sz    = (float*)(ws + 16384);         // 64 KB
    int*    idxb  = (int*)  (ws + 81920);         // 64 KB
    double* lossp = (double*)(ws + 147456);       // 128 KB
    int*    ghist = (int*)  (ws + 278528);        // 16 KB

    prep_all_kernel<<<PB_TOT, 256, 0, stream>>>(W, ema, z, wh, wl, se, out_ema,
                                                zh, sz, ghist);
    argmin_kernel<<<dim3(NROWS / 128, NCHUNK), 256, 0, stream>>>(
        zh, wh, wl, se, sz, bDD, bI, out_onehot);
    resolve_kernel<<<NROWS, 128, 0, stream>>>(z, W, se, sz, bDD, bI,
                                              idxb, out_idx, out_onehot);
    hist_kernel<<<16, 1024, 0, stream>>>(idxb, ghist);
    outputs_kernel<<<ZELEMS / 256, 256, 0, stream>>>(z, W, idxb, out_zq, out_z,
                                                     lossp);
    final_kernel<<<1, 1024, 0, stream>>>(ghist, lossp, out_loss, out_perp);
}

// Round 10
// 547.264 us; speedup vs baseline: 1.0082x; 1.0060x over previous
//
#include <hip/hip_runtime.h>
#include <math.h>

// ---------------------------------------------------------------------------
// VectorQuantizer3D — R18: 1-product MFMA argmin. Ledger R15-R17: all
// schedule/layout/overhead theories neutral (550±1); only MFMA-work removal
// (R14) ever moved time => argmin is MFMA-throughput-bound (2-product =
// 68.7 GFLOP ~ 115-170us at this tile size). Selection needs only ~1.6%
// relative dot accuracy: single zh*wh product has residual sigma ~4.4e-6;
// margins widened to 2.0e-4 -> 19-sigma budget, 3.2x above expected max|dm|
// over all 6.7e7 trials. Gap-test failures still caught by exact rescan.
// wl dead -> removed; sW halves to the validated 64B-row swizzled layout;
// LDS 35KB -> 4 blocks/CU. Cost: slow-path ~39%->49% (+8-12us resolve).
// Revert path: R14 2-product @1.5e-4 if absmax != 0.
// ---------------------------------------------------------------------------

#define N_E    4096
#define EDIM   256
#define SPAT   8192
#define NROWS  16384
#define ZELEMS 4194304
#define NCHUNK 32        // code chunks of 128
#define NLOSSPARTS 16384

// Output offsets (flat float32 in return order)
#define OFF_LOSS    0
#define OFF_ZQ      1
#define OFF_PERP    4194305
#define OFF_ONEHOT  4194306
#define OFF_IDX     71303170
#define OFF_ZOUT    71319554
#define OFF_EMA     75513858

// Scratch (float indices into out), all bases 16B-aligned, in regions
// rewritten by outputs_kernel AFTER their last scratch read:
//   out_zq region [1, 4194305):         wh [4,524292)
//   out_z  region [71319554, 75513858): bI [71319556,71843844),
//                                       bDD [71843844,72892420),
//                                       zh [72892420,74989572)
#define SCR_WH_F   4
#define SCR_BI_F   71319556
#define SCR_BDD_F  71843844
#define SCR_ZH_F   72892420

// 1-product error budget: |q_mfma - q_r6| <= 2|dm| + ulp(256) (~3.1e-5);
// dm = sum(z_lo*wh + zh*wl), sigma ~4.4e-6. MARG=2e-4 -> |dm| budget 8.4e-5
// = 19 sigma; expected max over 6.7e7 trials ~2.6e-5 (3.2x headroom).
#define MARG 2.0e-4f
#define GAPM 2.0e-4f

// prep_all blockIdx ranges
#define PB_W0   0        // 1024 blocks: W split + ema + se
#define PB_Z0   1024     // 512 blocks: split_z
#define PB_N0   1536     // 128 blocks: rnorm
#define PB_H0   1664     // 4 blocks: ghist zero
#define PB_TOT  1668

typedef unsigned short u16;
typedef short short8 __attribute__((ext_vector_type(8)));
typedef float f32x4 __attribute__((ext_vector_type(4)));
typedef const void __attribute__((address_space(1)))* gas1;
typedef void __attribute__((address_space(3)))* las3;
#define GLOAD16(g, l) __builtin_amdgcn_global_load_lds((gas1)(g), (las3)(l), 16, 0, 0)

__device__ __forceinline__ u16 f2bf(float f) {   // RTNE fp32 -> bf16
    unsigned u = __float_as_uint(f);
    return (u16)((u + 0x7fffu + ((u >> 16) & 1u)) >> 16);
}
__device__ __forceinline__ float bf2f(u16 h) {
    return __uint_as_float(((unsigned)h) << 16);
}

// ---------------------------------------------------------------------------
// K0: prep_all — fused {W split(hi) + ema + se} | split_z | rnorm | ghist 0.
// ---------------------------------------------------------------------------
__global__ __launch_bounds__(256) void prep_all_kernel(
        const float* __restrict__ W, const float* __restrict__ ema,
        const float* __restrict__ z,
        u16* __restrict__ wh,
        float* __restrict__ se, float* __restrict__ out_ema,
        u16* __restrict__ zh, float* __restrict__ sz,
        int* __restrict__ ghist) {
    __shared__ float t[128][65];       // split_z transpose tile
    __shared__ float szp[4][128];      // rnorm partials
    const int bx  = blockIdx.x;
    const int tid = threadIdx.x;

    if (bx < PB_Z0) {
        // ---- W prep: split(hi) + ema + se (VERBATIM R6 se numerics) ----
        const size_t tt = (size_t)bx * 256 + tid;       // 0..262143
        const int code = (int)(tt >> 6);
        const int lane = tid & 63;
        const float4 v = *(const float4*)(W + tt * 4);

        u16 h0 = f2bf(v.x), h1 = f2bf(v.y), h2 = f2bf(v.z), h3 = f2bf(v.w);
        uint2 hp;
        hp.x = (unsigned)h0 | ((unsigned)h1 << 16); hp.y = (unsigned)h2 | ((unsigned)h3 << 16);
        *(uint2*)(wh + tt * 4) = hp;

        const float4 e4 = *(const float4*)(ema + tt * 4);
        float4 o4;
        o4.x = 0.25f * e4.x + 0.75f * v.x;
        o4.y = 0.25f * e4.y + 0.75f * v.y;
        o4.z = 0.25f * e4.z + 0.75f * v.z;
        o4.w = 0.25f * e4.w + 0.75f * v.w;
        *(float4*)(out_ema + tt * 4) = o4;

        float s = v.x * v.x + v.y * v.y + v.z * v.z + v.w * v.w;
        #pragma unroll
        for (int off = 32; off > 0; off >>= 1) s += __shfl_down(s, off);
        if (lane == 0) se[code] = s;
    } else if (bx < PB_N0) {
        // ---- split_z: transposed bf16 hi [16384 rows][256 k] ----
        const int sub = bx - PB_Z0;
        const int sp0 = (sub & 127) * 64, c0 = ((sub >> 7) & 1) * 128, b = sub >> 8;
        const int wid = tid >> 6, lane = tid & 63;
        const float* zb = z + (size_t)b * (EDIM * SPAT);
        #pragma unroll
        for (int it = 0; it < 32; ++it) {
            const int cl = wid + 4 * it;                 // 0..127
            t[cl][lane] = zb[(size_t)(c0 + cl) * SPAT + sp0 + lane];
        }
        __syncthreads();
        #pragma unroll
        for (int it = 0; it < 16; ++it) {
            const int r = wid + 4 * it;                  // 0..63
            const float v0 = t[2 * lane][r], v1 = t[2 * lane + 1][r];
            const u16 h0 = f2bf(v0), h1 = f2bf(v1);
            const size_t row = (size_t)b * SPAT + sp0 + r;
            ((unsigned*)zh)[row * 128 + (c0 >> 1) + lane] = (unsigned)h0 | ((unsigned)h1 << 16);
        }
    } else if (bx < PB_H0) {
        // ---- rnorm (R6 exact order; 256-thread variant, identical partials)
        const int r0 = (bx - PB_N0) * 128;
        const int bb = r0 >> 13;
        const int sp0 = r0 & (SPAT - 1);
        const float* zb = z + (size_t)bb * (EDIM * SPAT) + sp0;
        const int lr = tid & 127, kh = tid >> 7;         // kh 0..1
        #pragma unroll
        for (int h = 0; h < 2; ++h) {
            const int kq = kh * 2 + h;                   // covers 0..3
            float s = 0.f;
            const float* p = zb + lr + (size_t)(kq * 64) * SPAT;
            for (int k = 0; k < 64; ++k) {
                float v = p[(size_t)k * SPAT];
                s += v * v;
            }
            szp[kq][lr] = s;
        }
        __syncthreads();
        if (tid < 128)
            sz[r0 + tid] = ((szp[0][tid] + szp[1][tid]) + szp[2][tid]) + szp[3][tid];
    } else {
        // ---- ghist zero: 4 blocks x 1024 entries ----
        const int base = (bx - PB_H0) * 1024;
        #pragma unroll
        for (int j = 0; j < 4; ++j) ghist[base + j * 256 + tid] = 0;
    }
}

// ---------------------------------------------------------------------------
// K1: 1-product MFMA argmin + per-chunk top-2 + one-hot zero slice.
// sW and sZ both [2][128][32] u16 (64-B rows), u^((row>>1)&3) swizzle
// (uniform 2-way bank aliasing = free). 35 KB LDS -> 4 blocks/CU.
// ---------------------------------------------------------------------------
__global__ __launch_bounds__(256, 4) void argmin_kernel(
        const u16* __restrict__ zh, const u16* __restrict__ wh,
        const float* __restrict__ se, const float* __restrict__ sz,
        float* __restrict__ bDD, int* __restrict__ bI,
        float* __restrict__ out_onehot) {
    __shared__ u16 sW[2][128][32];  // 16 KB: [buf][code][hi32]
    __shared__ u16 sZ[2][128][32];  // 16 KB: [buf][row ][hi32]
    __shared__ float mD[2][128];
    __shared__ int   mI[2][128];
    __shared__ float mD2[2][128];

    const int tid = threadIdx.x;
    const int wid = tid >> 6, lane = tid & 63;
    const int wm = wid >> 1, wn = wid & 1;
    const int lq = lane >> 4, lr = lane & 15;
    const int chunk = blockIdx.y;          // 0..31
    const int rbase = blockIdx.x * 128;
    const int cbase = chunk * 128;

    // staging: 512 16B-chunks per array per buffer, 2/thread each.
    // chunk o -> row=o>>2, pos g=o&3; data chunk u = g ^ ((row>>1)&3).
    const u16* gw[2]; const u16* gz[2];
    #pragma unroll
    for (int j = 0; j < 2; ++j) {
        const int o = j * 256 + tid;
        const int row = o >> 2, g = o & 3, u = g ^ ((row >> 1) & 3);
        gw[j] = wh + (size_t)(cbase + row) * EDIM + u * 8;
        gz[j] = zh + (size_t)(rbase + row) * EDIM + u * 8;
    }

    char* sWb = (char*)&sW[0][0][0];
    char* sZb = (char*)&sZ[0][0][0];

    // fragment LDS byte offsets within a buffer (stage-invariant)
    int aoff[4], boff[4];
    #pragma unroll
    for (int tt = 0; tt < 4; ++tt) {
        const int cl = wn * 64 + tt * 16 + lr;
        aoff[tt] = cl * 64 + (lq ^ ((cl >> 1) & 3)) * 16;
        const int rl = wm * 64 + tt * 16 + lr;
        boff[tt] = rl * 64 + (lq ^ ((rl >> 1) & 3)) * 16;
    }

    f32x4 acc[4][4];
    #pragma unroll
    for (int ci = 0; ci < 4; ++ci)
        #pragma unroll
        for (int rj = 0; rj < 4; ++rj) {
            f32x4 zzz = {0.f, 0.f, 0.f, 0.f};
            acc[ci][rj] = zzz;
        }

    #define STAGE(b) do {                                                      \
        _Pragma("unroll")                                                      \
        for (int j = 0; j < 2; ++j) {                                          \
            GLOAD16(gw[j], sWb + (b) * 8192 + (j * 256 + wid * 64) * 16);      \
            GLOAD16(gz[j], sZb + (b) * 8192 + (j * 256 + wid * 64) * 16);      \
            gw[j] += 32; gz[j] += 32;                                          \
        }                                                                      \
    } while (0)

    STAGE(0);
    __syncthreads();                       // drain prologue -> buf0 ready

    for (int k0 = 0; k0 < 8; ++k0) {
        const int cur = k0 & 1;
        if (k0 < 7) STAGE(cur ^ 1);        // next tile in flight during compute

        const char* wbase = sWb + cur * 8192;
        const char* zbase = sZb + cur * 8192;
        short8 zb[4];
        #pragma unroll
        for (int rj = 0; rj < 4; ++rj)
            zb[rj] = *(const short8*)(zbase + boff[rj]);
        #pragma unroll
        for (int ci = 0; ci < 4; ++ci) {
            const short8 wah = *(const short8*)(wbase + aoff[ci]);
            #pragma unroll
            for (int rj = 0; rj < 4; ++rj)
                acc[ci][rj] = __builtin_amdgcn_mfma_f32_16x16x32_bf16(wah, zb[rj], acc[ci][rj], 0, 0, 0);
        }
        __syncthreads();                   // drains next-tile loads + read fence
    }
    #undef STAGE

    // ---- epilogue: per-chunk quantized top-2 (value-only second) ----
    f32x4 sev[4];
    #pragma unroll
    for (int ci = 0; ci < 4; ++ci)
        sev[ci] = *(const f32x4*)(se + cbase + wn * 64 + ci * 16 + lq * 4);

    #pragma unroll
    for (int rj = 0; rj < 4; ++rj) {
        const int rloc = wm * 64 + rj * 16 + lr;
        const float szr = sz[rbase + rloc];
        float b1 = 3.4e38f, b2 = 3.4e38f; int bi1 = 0x7fffffff;
        #pragma unroll
        for (int ci = 0; ci < 4; ++ci) {
            #pragma unroll
            for (int r = 0; r < 4; ++r) {
                const float q = (szr + sev[ci][r]) - 2.0f * acc[ci][rj][r];
                const int code = cbase + wn * 64 + ci * 16 + lq * 4 + r;
                if (q < b1 || (q == b1 && code < bi1)) {
                    b2 = b1; b1 = q; bi1 = code;
                } else if (q < b2) {
                    b2 = q;
                }
            }
        }
        #pragma unroll
        for (int mask = 16; mask <= 32; mask <<= 1) {
            const float od1 = __shfl_xor(b1, mask);
            const int   oi1 = __shfl_xor(bi1, mask);
            const float od2 = __shfl_xor(b2, mask);
            const bool ot = (od1 < b1) || (od1 == b1 && oi1 < bi1);
            if (ot) { b2 = fminf(b1, od2); b1 = od1; bi1 = oi1; }
            else    { b2 = fminf(b2, od1); }
        }
        if (lq == 0) {
            mD[wn][rloc]  = b1;
            mI[wn][rloc]  = bi1;
            mD2[wn][rloc] = b2;
        }
    }
    __syncthreads();
    if (tid < 128) {
        const float d0 = mD[0][tid], d1 = mD[1][tid];
        const int   i0 = mI[0][tid], i1 = mI[1][tid];
        const float s0 = mD2[0][tid], s1 = mD2[1][tid];
        float dm, sm; int im;
        if (d1 < d0 || (d1 == d0 && i1 < i0)) { dm = d1; im = i1; sm = fminf(s1, d0); }
        else                                  { dm = d0; im = i0; sm = fminf(s0, d1); }
        const int row = rbase + tid;
        float2 p; p.x = dm; p.y = sm;
        *(float2*)(bDD + (size_t)row * 64 + chunk * 2) = p;
        bI[(size_t)row * 32 + chunk] = im;
    }

    // ---- one-hot zero slice (64 KB per block; drains under block exit) ----
    {
        const int slice = blockIdx.x * 32 + blockIdx.y;   // 0..4095, bijective
        float* oh = out_onehot + (size_t)slice * 16384;
        const float4 z4 = {0.f, 0.f, 0.f, 0.f};
        #pragma unroll
        for (int it = 0; it < 16; ++it)
            *(float4*)(oh + it * 1024 + tid * 4) = z4;
    }
}

// ---------------------------------------------------------------------------
// K1b: resolve — 128 threads/block. Fast path (gap > GAPM): accept MFMA
// winner. Slow path: R10-validated exact serial-k rescan of candidate chunks.
// ---------------------------------------------------------------------------
__global__ __launch_bounds__(128) void resolve_kernel(
        const float* __restrict__ z, const float* __restrict__ W,
        const float* __restrict__ se, const float* __restrict__ sz,
        const float* __restrict__ bDD, const int* __restrict__ bI,
        int* __restrict__ idx_ws, float* __restrict__ out_idx,
        float* __restrict__ out_onehot) {
    __shared__ float zr[EDIM];
    __shared__ float rd[128];
    __shared__ int   ri[128];
    __shared__ unsigned smask;
    __shared__ int swin, sskip;
    const int row = blockIdx.x;
    const int tid = threadIdx.x;

    if (tid < 64) {
        const int c = tid & 31;
        const float2 dd = *(const float2*)(bDD + (size_t)row * 64 + c * 2);
        const int    i1 = bI[(size_t)row * 32 + c];
        const float d1 = dd.x;
        float b1 = dd.x, b2 = dd.y; int j1 = i1;
        #pragma unroll
        for (int mask = 16; mask > 0; mask >>= 1) {
            const float od1 = __shfl_xor(b1, mask);
            const int   oj1 = __shfl_xor(j1, mask);
            const float od2 = __shfl_xor(b2, mask);
            const bool ot = (od1 < b1) || (od1 == b1 && oj1 < j1);
            if (ot) { b2 = fminf(b1, od2); b1 = od1; j1 = oj1; }
            else    { b2 = fminf(b2, od1); }
        }
        const unsigned long long m = __ballot(d1 <= b1 + MARG);
        if (tid == 0) {
            smask = (unsigned)(m & 0xffffffffu);
            swin  = j1;
            sskip = (b2 - b1 > GAPM) ? 1 : 0;
        }
    }
    __syncthreads();

    if (sskip) {
        if (tid == 0) {
            idx_ws[row]  = swin;
            out_idx[row] = (float)swin;
            out_onehot[(size_t)row * N_E + swin] = 1.0f;
        }
        return;
    }

    // slow path: exact rescan (R10-validated numerics, unchanged)
    {
        const int b = row >> 13, sp = row & (SPAT - 1);
        zr[tid]       = z[(size_t)b * (EDIM * SPAT) + (size_t)tid * SPAT + sp];
        zr[tid + 128] = z[(size_t)b * (EDIM * SPAT) + (size_t)(tid + 128) * SPAT + sp];
    }
    __syncthreads();

    const float szr = sz[row];
    unsigned cmask = smask;
    float best = 3.4e38f; int bi = 0x7fffffff;
    while (cmask) {
        const int cc = __ffs(cmask) - 1;
        cmask &= cmask - 1;
        const int code = cc * 128 + tid;
        const float* wr = W + (size_t)code * EDIM;
        float s = 0.f;
        for (int k = 0; k < EDIM; ++k) s += zr[k] * wr[k];   // serial k
        const float q = (szr + se[code]) - 2.0f * s;
        if (q < best || (q == best && code < bi)) { best = q; bi = code; }
    }
    rd[tid] = best; ri[tid] = bi;
    __syncthreads();
    for (int off = 64; off > 0; off >>= 1) {
        if (tid < off) {
            const float od = rd[tid + off]; const int oi = ri[tid + off];
            if (od < rd[tid] || (od == rd[tid] && oi < ri[tid])) {
                rd[tid] = od; ri[tid] = oi;
            }
        }
        __syncthreads();
    }
    if (tid == 0) {
        const int ii = ri[0];
        idx_ws[row]  = ii;
        out_idx[row] = (float)ii;
        out_onehot[(size_t)row * N_E + ii] = 1.0f;
    }
}

// ---------------------------------------------------------------------------
// K1c: hist — 16 blocks x 1024 rows, private LDS histogram + global merge.
// ---------------------------------------------------------------------------
__global__ __launch_bounds__(1024) void hist_kernel(const int* __restrict__ idx,
                                                    int* __restrict__ ghist) {
    __shared__ int lh[N_E];
    const int tid = threadIdx.x;
    for (int i = tid; i < N_E; i += 1024) lh[i] = 0;
    __syncthreads();
    atomicAdd(&lh[idx[blockIdx.x * 1024 + tid]], 1);
    __syncthreads();
    for (int c = tid; c < N_E; c += 1024) {
        const int v = lh[c];
        if (v) atomicAdd(&ghist[c], v);
    }
}

// ---------------------------------------------------------------------------
// K2: z_q_out, z_out, loss partials — unchanged from R6.
// ---------------------------------------------------------------------------
__global__ __launch_bounds__(256) void outputs_kernel(
        const float* __restrict__ z, const float* __restrict__ W,
        const int* __restrict__ idx,
        float* __restrict__ zq_out, float* __restrict__ z_out,
        double* __restrict__ loss_parts) {
    const int t  = blockIdx.x * 256 + threadIdx.x;
    const float zv = z[t];
    const int sp = t & (SPAT - 1);
    const int c  = (t >> 13) & 255;
    const int b  = t >> 21;
    const int n  = (b << 13) + sp;
    const int id = idx[n];
    const float e    = W[id * EDIM + c];
    const float diff = e - zv;
    zq_out[t] = zv + diff;
    z_out[t]  = zv;

    double ds = (double)(diff * diff);
    #pragma unroll
    for (int off = 32; off > 0; off >>= 1) ds += __shfl_down(ds, off);
    __shared__ double bsum[4];
    const int lane = threadIdx.x & 63, w = threadIdx.x >> 6;
    if (lane == 0) bsum[w] = ds;
    __syncthreads();
    if (threadIdx.x == 0)
        loss_parts[blockIdx.x] = bsum[0] + bsum[1] + bsum[2] + bsum[3];
}

// ---------------------------------------------------------------------------
// K4: perplexity (from ghist, identical c-mapping/order) + loss finalize.
// ---------------------------------------------------------------------------
__global__ __launch_bounds__(1024) void final_kernel(
        const int* __restrict__ ghist, const double* __restrict__ loss_parts,
        float* __restrict__ out_loss, float* __restrict__ out_perp) {
    __shared__ float ps[1024];
    __shared__ double ls[1024];
    const int tid = threadIdx.x;

    float s = 0.f;
    for (int c = tid; c < N_E; c += 1024) {
        const float p = (float)ghist[c] * (1.0f / (float)NROWS);
        s += p * logf(p + 1e-10f);
    }
    double l = 0.0;
    for (int c = tid; c < NLOSSPARTS; c += 1024) l += loss_parts[c];
    ps[tid] = s;
    ls[tid] = l;
    __syncthreads();
    for (int off = 512; off > 0; off >>= 1) {
        if (tid < off) {
            ps[tid] += ps[tid + off];
            ls[tid] += ls[tid + off];
        }
        __syncthreads();
    }
    if (tid == 0) {
        *out_perp = expf(-ps[0]);
        const float m = (float)(ls[0] / (double)ZELEMS);
        *out_loss = m + 0.25f * m;
    }
}

// ---------------------------------------------------------------------------
extern "C" void kernel_launch(void* const* d_in, const int* in_sizes, int n_in,
                              void* d_out, int out_size, void* d_ws, size_t ws_size,
                              hipStream_t stream) {
    const float* z   = (const float*)d_in[0];
    const float* W   = (const float*)d_in[1];
    const float* ema = (const float*)d_in[2];
    float* out = (float*)d_out;

    float* out_loss   = out + OFF_LOSS;
    float* out_zq     = out + OFF_ZQ;
    float* out_perp   = out + OFF_PERP;
    float* out_onehot = out + OFF_ONEHOT;
    float* out_idx    = out + OFF_IDX;
    float* out_z      = out + OFF_ZOUT;
    float* out_ema    = out + OFF_EMA;

    // scratch inside later-overwritten output regions (16B-aligned bases)
    u16*   wh  = (u16*)(out + SCR_WH_F);
    int*   bI  = (int*)(out + SCR_BI_F);
    float* bDD = out + SCR_BDD_F;
    u16*   zh  = (u16*)(out + SCR_ZH_F);

    // workspace
    char* ws = (char*)d_ws;
    float*  se    = (float*)ws;                   // 16 KB
    float*  sz    = (float*)(ws + 16384);         // 64 KB
    int*    idxb  = (int*)  (ws + 81920);         // 64 KB
    double* lossp = (double*)(ws + 147456);       // 128 KB
    int*    ghist = (int*)  (ws + 278528);        // 16 KB

    prep_all_kernel<<<PB_TOT, 256, 0, stream>>>(W, ema, z, wh, se, out_ema,
                                                zh, sz, ghist);
    argmin_kernel<<<dim3(NROWS / 128, NCHUNK), 256, 0, stream>>>(
        zh, wh, se, sz, bDD, bI, out_onehot);
    resolve_kernel<<<NROWS, 128, 0, stream>>>(z, W, se, sz, bDD, bI,
                                              idxb, out_idx, out_onehot);
    hist_kernel<<<16, 1024, 0, stream>>>(idxb, ghist);
    outputs_kernel<<<ZELEMS / 256, 256, 0, stream>>>(z, W, idxb, out_zq, out_z,
                                                     lossp);
    final_kernel<<<1, 1024, 0, stream>>>(ghist, lossp, out_loss, out_perp);
}

// Round 11
// 518.188 us; speedup vs baseline: 1.0648x; 1.0561x over previous
//
#include <hip/hip_runtime.h>
#include <math.h>

// ---------------------------------------------------------------------------
// VectorQuantizer3D — R19: single-variable A/B vs R18: MARG/GAPM 2.0e-4 ->
// 1.3e-4. Rationale: R18 nulled the MFMA-throughput theory (halving MFMAs
// changed nothing); the only lever with a MEASURED effect on our portion is
// resolve's slow-path fraction (R13: +31us at widened margins; R14 won it
// back). 1.3e-4 budget = (1.3e-4 - ulp)/2 = 5.0e-5 = 18 sigma of the
// 1-product split residual (sigma 2.8e-6), 2.9x the expected MAX |dm| over
// all 6.7e7 trials. Slow-path ~49% -> ~35%. Everything else byte-identical
// to R18 (absmax 0.0 validated). Revert path: 2.0e-4.
// ---------------------------------------------------------------------------

#define N_E    4096
#define EDIM   256
#define SPAT   8192
#define NROWS  16384
#define ZELEMS 4194304
#define NCHUNK 32        // code chunks of 128
#define NLOSSPARTS 16384

// Output offsets (flat float32 in return order)
#define OFF_LOSS    0
#define OFF_ZQ      1
#define OFF_PERP    4194305
#define OFF_ONEHOT  4194306
#define OFF_IDX     71303170
#define OFF_ZOUT    71319554
#define OFF_EMA     75513858

// Scratch (float indices into out), all bases 16B-aligned, in regions
// rewritten by outputs_kernel AFTER their last scratch read:
//   out_zq region [1, 4194305):         wh [4,524292)
//   out_z  region [71319554, 75513858): bI [71319556,71843844),
//                                       bDD [71843844,72892420),
//                                       zh [72892420,74989572)
#define SCR_WH_F   4
#define SCR_BI_F   71319556
#define SCR_BDD_F  71843844
#define SCR_ZH_F   72892420

// 1-product error budget at 1.3e-4: |q_mfma - q_r6| <= 2|dm| + ulp(512)
// (3.05e-5); dm = sum(z_lo*wh + zh*wl), sigma ~2.8e-6 -> 18-sigma budget,
// 2.9x expected max over 6.7e7 trials. Gap-test failures caught by rescan.
#define MARG 1.3e-4f
#define GAPM 1.3e-4f

// prep_all blockIdx ranges
#define PB_W0   0        // 1024 blocks: W split + ema + se
#define PB_Z0   1024     // 512 blocks: split_z
#define PB_N0   1536     // 128 blocks: rnorm
#define PB_H0   1664     // 4 blocks: ghist zero
#define PB_TOT  1668

typedef unsigned short u16;
typedef short short8 __attribute__((ext_vector_type(8)));
typedef float f32x4 __attribute__((ext_vector_type(4)));
typedef const void __attribute__((address_space(1)))* gas1;
typedef void __attribute__((address_space(3)))* las3;
#define GLOAD16(g, l) __builtin_amdgcn_global_load_lds((gas1)(g), (las3)(l), 16, 0, 0)

__device__ __forceinline__ u16 f2bf(float f) {   // RTNE fp32 -> bf16
    unsigned u = __float_as_uint(f);
    return (u16)((u + 0x7fffu + ((u >> 16) & 1u)) >> 16);
}
__device__ __forceinline__ float bf2f(u16 h) {
    return __uint_as_float(((unsigned)h) << 16);
}

// ---------------------------------------------------------------------------
// K0: prep_all — fused {W split(hi) + ema + se} | split_z | rnorm | ghist 0.
// ---------------------------------------------------------------------------
__global__ __launch_bounds__(256) void prep_all_kernel(
        const float* __restrict__ W, const float* __restrict__ ema,
        const float* __restrict__ z,
        u16* __restrict__ wh,
        float* __restrict__ se, float* __restrict__ out_ema,
        u16* __restrict__ zh, float* __restrict__ sz,
        int* __restrict__ ghist) {
    __shared__ float t[128][65];       // split_z transpose tile
    __shared__ float szp[4][128];      // rnorm partials
    const int bx  = blockIdx.x;
    const int tid = threadIdx.x;

    if (bx < PB_Z0) {
        // ---- W prep: split(hi) + ema + se (VERBATIM R6 se numerics) ----
        const size_t tt = (size_t)bx * 256 + tid;       // 0..262143
        const int code = (int)(tt >> 6);
        const int lane = tid & 63;
        const float4 v = *(const float4*)(W + tt * 4);

        u16 h0 = f2bf(v.x), h1 = f2bf(v.y), h2 = f2bf(v.z), h3 = f2bf(v.w);
        uint2 hp;
        hp.x = (unsigned)h0 | ((unsigned)h1 << 16); hp.y = (unsigned)h2 | ((unsigned)h3 << 16);
        *(uint2*)(wh + tt * 4) = hp;

        const float4 e4 = *(const float4*)(ema + tt * 4);
        float4 o4;
        o4.x = 0.25f * e4.x + 0.75f * v.x;
        o4.y = 0.25f * e4.y + 0.75f * v.y;
        o4.z = 0.25f * e4.z + 0.75f * v.z;
        o4.w = 0.25f * e4.w + 0.75f * v.w;
        *(float4*)(out_ema + tt * 4) = o4;

        float s = v.x * v.x + v.y * v.y + v.z * v.z + v.w * v.w;
        #pragma unroll
        for (int off = 32; off > 0; off >>= 1) s += __shfl_down(s, off);
        if (lane == 0) se[code] = s;
    } else if (bx < PB_N0) {
        // ---- split_z: transposed bf16 hi [16384 rows][256 k] ----
        const int sub = bx - PB_Z0;
        const int sp0 = (sub & 127) * 64, c0 = ((sub >> 7) & 1) * 128, b = sub >> 8;
        const int wid = tid >> 6, lane = tid & 63;
        const float* zb = z + (size_t)b * (EDIM * SPAT);
        #pragma unroll
        for (int it = 0; it < 32; ++it) {
            const int cl = wid + 4 * it;                 // 0..127
            t[cl][lane] = zb[(size_t)(c0 + cl) * SPAT + sp0 + lane];
        }
        __syncthreads();
        #pragma unroll
        for (int it = 0; it < 16; ++it) {
            const int r = wid + 4 * it;                  // 0..63
            const float v0 = t[2 * lane][r], v1 = t[2 * lane + 1][r];
            const u16 h0 = f2bf(v0), h1 = f2bf(v1);
            const size_t row = (size_t)b * SPAT + sp0 + r;
            ((unsigned*)zh)[row * 128 + (c0 >> 1) + lane] = (unsigned)h0 | ((unsigned)h1 << 16);
        }
    } else if (bx < PB_H0) {
        // ---- rnorm (R6 exact order; 256-thread variant, identical partials)
        const int r0 = (bx - PB_N0) * 128;
        const int bb = r0 >> 13;
        const int sp0 = r0 & (SPAT - 1);
        const float* zb = z + (size_t)bb * (EDIM * SPAT) + sp0;
        const int lr = tid & 127, kh = tid >> 7;         // kh 0..1
        #pragma unroll
        for (int h = 0; h < 2; ++h) {
            const int kq = kh * 2 + h;                   // covers 0..3
            float s = 0.f;
            const float* p = zb + lr + (size_t)(kq * 64) * SPAT;
            for (int k = 0; k < 64; ++k) {
                float v = p[(size_t)k * SPAT];
                s += v * v;
            }
            szp[kq][lr] = s;
        }
        __syncthreads();
        if (tid < 128)
            sz[r0 + tid] = ((szp[0][tid] + szp[1][tid]) + szp[2][tid]) + szp[3][tid];
    } else {
        // ---- ghist zero: 4 blocks x 1024 entries ----
        const int base = (bx - PB_H0) * 1024;
        #pragma unroll
        for (int j = 0; j < 4; ++j) ghist[base + j * 256 + tid] = 0;
    }
}

// ---------------------------------------------------------------------------
// K1: 1-product MFMA argmin + per-chunk top-2 + one-hot zero slice.
// sW and sZ both [2][128][32] u16 (64-B rows), u^((row>>1)&3) swizzle.
// ---------------------------------------------------------------------------
__global__ __launch_bounds__(256, 4) void argmin_kernel(
        const u16* __restrict__ zh, const u16* __restrict__ wh,
        const float* __restrict__ se, const float* __restrict__ sz,
        float* __restrict__ bDD, int* __restrict__ bI,
        float* __restrict__ out_onehot) {
    __shared__ u16 sW[2][128][32];  // 16 KB: [buf][code][hi32]
    __shared__ u16 sZ[2][128][32];  // 16 KB: [buf][row ][hi32]
    __shared__ float mD[2][128];
    __shared__ int   mI[2][128];
    __shared__ float mD2[2][128];

    const int tid = threadIdx.x;
    const int wid = tid >> 6, lane = tid & 63;
    const int wm = wid >> 1, wn = wid & 1;
    const int lq = lane >> 4, lr = lane & 15;
    const int chunk = blockIdx.y;          // 0..31
    const int rbase = blockIdx.x * 128;
    const int cbase = chunk * 128;

    const u16* gw[2]; const u16* gz[2];
    #pragma unroll
    for (int j = 0; j < 2; ++j) {
        const int o = j * 256 + tid;
        const int row = o >> 2, g = o & 3, u = g ^ ((row >> 1) & 3);
        gw[j] = wh + (size_t)(cbase + row) * EDIM + u * 8;
        gz[j] = zh + (size_t)(rbase + row) * EDIM + u * 8;
    }

    char* sWb = (char*)&sW[0][0][0];
    char* sZb = (char*)&sZ[0][0][0];

    int aoff[4], boff[4];
    #pragma unroll
    for (int tt = 0; tt < 4; ++tt) {
        const int cl = wn * 64 + tt * 16 + lr;
        aoff[tt] = cl * 64 + (lq ^ ((cl >> 1) & 3)) * 16;
        const int rl = wm * 64 + tt * 16 + lr;
        boff[tt] = rl * 64 + (lq ^ ((rl >> 1) & 3)) * 16;
    }

    f32x4 acc[4][4];
    #pragma unroll
    for (int ci = 0; ci < 4; ++ci)
        #pragma unroll
        for (int rj = 0; rj < 4; ++rj) {
            f32x4 zzz = {0.f, 0.f, 0.f, 0.f};
            acc[ci][rj] = zzz;
        }

    #define STAGE(b) do {                                                      \
        _Pragma("unroll")                                                      \
        for (int j = 0; j < 2; ++j) {                                          \
            GLOAD16(gw[j], sWb + (b) * 8192 + (j * 256 + wid * 64) * 16);      \
            GLOAD16(gz[j], sZb + (b) * 8192 + (j * 256 + wid * 64) * 16);      \
            gw[j] += 32; gz[j] += 32;                                          \
        }                                                                      \
    } while (0)

    STAGE(0);
    __syncthreads();                       // drain prologue -> buf0 ready

    for (int k0 = 0; k0 < 8; ++k0) {
        const int cur = k0 & 1;
        if (k0 < 7) STAGE(cur ^ 1);        // next tile in flight during compute

        const char* wbase = sWb + cur * 8192;
        const char* zbase = sZb + cur * 8192;
        short8 zb[4];
        #pragma unroll
        for (int rj = 0; rj < 4; ++rj)
            zb[rj] = *(const short8*)(zbase + boff[rj]);
        #pragma unroll
        for (int ci = 0; ci < 4; ++ci) {
            const short8 wah = *(const short8*)(wbase + aoff[ci]);
            #pragma unroll
            for (int rj = 0; rj < 4; ++rj)
                acc[ci][rj] = __builtin_amdgcn_mfma_f32_16x16x32_bf16(wah, zb[rj], acc[ci][rj], 0, 0, 0);
        }
        __syncthreads();                   // drains next-tile loads + read fence
    }
    #undef STAGE

    // ---- epilogue: per-chunk quantized top-2 (value-only second) ----
    f32x4 sev[4];
    #pragma unroll
    for (int ci = 0; ci < 4; ++ci)
        sev[ci] = *(const f32x4*)(se + cbase + wn * 64 + ci * 16 + lq * 4);

    #pragma unroll
    for (int rj = 0; rj < 4; ++rj) {
        const int rloc = wm * 64 + rj * 16 + lr;
        const float szr = sz[rbase + rloc];
        float b1 = 3.4e38f, b2 = 3.4e38f; int bi1 = 0x7fffffff;
        #pragma unroll
        for (int ci = 0; ci < 4; ++ci) {
            #pragma unroll
            for (int r = 0; r < 4; ++r) {
                const float q = (szr + sev[ci][r]) - 2.0f * acc[ci][rj][r];
                const int code = cbase + wn * 64 + ci * 16 + lq * 4 + r;
                if (q < b1 || (q == b1 && code < bi1)) {
                    b2 = b1; b1 = q; bi1 = code;
                } else if (q < b2) {
                    b2 = q;
                }
            }
        }
        #pragma unroll
        for (int mask = 16; mask <= 32; mask <<= 1) {
            const float od1 = __shfl_xor(b1, mask);
            const int   oi1 = __shfl_xor(bi1, mask);
            const float od2 = __shfl_xor(b2, mask);
            const bool ot = (od1 < b1) || (od1 == b1 && oi1 < bi1);
            if (ot) { b2 = fminf(b1, od2); b1 = od1; bi1 = oi1; }
            else    { b2 = fminf(b2, od1); }
        }
        if (lq == 0) {
            mD[wn][rloc]  = b1;
            mI[wn][rloc]  = bi1;
            mD2[wn][rloc] = b2;
        }
    }
    __syncthreads();
    if (tid < 128) {
        const float d0 = mD[0][tid], d1 = mD[1][tid];
        const int   i0 = mI[0][tid], i1 = mI[1][tid];
        const float s0 = mD2[0][tid], s1 = mD2[1][tid];
        float dm, sm; int im;
        if (d1 < d0 || (d1 == d0 && i1 < i0)) { dm = d1; im = i1; sm = fminf(s1, d0); }
        else                                  { dm = d0; im = i0; sm = fminf(s0, d1); }
        const int row = rbase + tid;
        float2 p; p.x = dm; p.y = sm;
        *(float2*)(bDD + (size_t)row * 64 + chunk * 2) = p;
        bI[(size_t)row * 32 + chunk] = im;
    }

    // ---- one-hot zero slice (64 KB per block; drains under block exit) ----
    {
        const int slice = blockIdx.x * 32 + blockIdx.y;   // 0..4095, bijective
        float* oh = out_onehot + (size_t)slice * 16384;
        const float4 z4 = {0.f, 0.f, 0.f, 0.f};
        #pragma unroll
        for (int it = 0; it < 16; ++it)
            *(float4*)(oh + it * 1024 + tid * 4) = z4;
    }
}

// ---------------------------------------------------------------------------
// K1b: resolve — 128 threads/block. Fast path (gap > GAPM): accept MFMA
// winner. Slow path: R10-validated exact serial-k rescan of candidate chunks.
// ---------------------------------------------------------------------------
__global__ __launch_bounds__(128) void resolve_kernel(
        const float* __restrict__ z, const float* __restrict__ W,
        const float* __restrict__ se, const float* __restrict__ sz,
        const float* __restrict__ bDD, const int* __restrict__ bI,
        int* __restrict__ idx_ws, float* __restrict__ out_idx,
        float* __restrict__ out_onehot) {
    __shared__ float zr[EDIM];
    __shared__ float rd[128];
    __shared__ int   ri[128];
    __shared__ unsigned smask;
    __shared__ int swin, sskip;
    const int row = blockIdx.x;
    const int tid = threadIdx.x;

    if (tid < 64) {
        const int c = tid & 31;
        const float2 dd = *(const float2*)(bDD + (size_t)row * 64 + c * 2);
        const int    i1 = bI[(size_t)row * 32 + c];
        const float d1 = dd.x;
        float b1 = dd.x, b2 = dd.y; int j1 = i1;
        #pragma unroll
        for (int mask = 16; mask > 0; mask >>= 1) {
            const float od1 = __shfl_xor(b1, mask);
            const int   oj1 = __shfl_xor(j1, mask);
            const float od2 = __shfl_xor(b2, mask);
            const bool ot = (od1 < b1) || (od1 == b1 && oj1 < j1);
            if (ot) { b2 = fminf(b1, od2); b1 = od1; j1 = oj1; }
            else    { b2 = fminf(b2, od1); }
        }
        const unsigned long long m = __ballot(d1 <= b1 + MARG);
        if (tid == 0) {
            smask = (unsigned)(m & 0xffffffffu);
            swin  = j1;
            sskip = (b2 - b1 > GAPM) ? 1 : 0;
        }
    }
    __syncthreads();

    if (sskip) {
        if (tid == 0) {
            idx_ws[row]  = swin;
            out_idx[row] = (float)swin;
            out_onehot[(size_t)row * N_E + swin] = 1.0f;
        }
        return;
    }

    // slow path: exact rescan (R10-validated numerics, unchanged)
    {
        const int b = row >> 13, sp = row & (SPAT - 1);
        zr[tid]       = z[(size_t)b * (EDIM * SPAT) + (size_t)tid * SPAT + sp];
        zr[tid + 128] = z[(size_t)b * (EDIM * SPAT) + (size_t)(tid + 128) * SPAT + sp];
    }
    __syncthreads();

    const float szr = sz[row];
    unsigned cmask = smask;
    float best = 3.4e38f; int bi = 0x7fffffff;
    while (cmask) {
        const int cc = __ffs(cmask) - 1;
        cmask &= cmask - 1;
        const int code = cc * 128 + tid;
        const float* wr = W + (size_t)code * EDIM;
        float s = 0.f;
        for (int k = 0; k < EDIM; ++k) s += zr[k] * wr[k];   // serial k
        const float q = (szr + se[code]) - 2.0f * s;
        if (q < best || (q == best && code < bi)) { best = q; bi = code; }
    }
    rd[tid] = best; ri[tid] = bi;
    __syncthreads();
    for (int off = 64; off > 0; off >>= 1) {
        if (tid < off) {
            const float od = rd[tid + off]; const int oi = ri[tid + off];
            if (od < rd[tid] || (od == rd[tid] && oi < ri[tid])) {
                rd[tid] = od; ri[tid] = oi;
            }
        }
        __syncthreads();
    }
    if (tid == 0) {
        const int ii = ri[0];
        idx_ws[row]  = ii;
        out_idx[row] = (float)ii;
        out_onehot[(size_t)row * N_E + ii] = 1.0f;
    }
}

// ---------------------------------------------------------------------------
// K1c: hist — 16 blocks x 1024 rows, private LDS histogram + global merge.
// ---------------------------------------------------------------------------
__global__ __launch_bounds__(1024) void hist_kernel(const int* __restrict__ idx,
                                                    int* __restrict__ ghist) {
    __shared__ int lh[N_E];
    const int tid = threadIdx.x;
    for (int i = tid; i < N_E; i += 1024) lh[i] = 0;
    __syncthreads();
    atomicAdd(&lh[idx[blockIdx.x * 1024 + tid]], 1);
    __syncthreads();
    for (int c = tid; c < N_E; c += 1024) {
        const int v = lh[c];
        if (v) atomicAdd(&ghist[c], v);
    }
}

// ---------------------------------------------------------------------------
// K2: z_q_out, z_out, loss partials — unchanged from R6.
// ---------------------------------------------------------------------------
__global__ __launch_bounds__(256) void outputs_kernel(
        const float* __restrict__ z, const float* __restrict__ W,
        const int* __restrict__ idx,
        float* __restrict__ zq_out, float* __restrict__ z_out,
        double* __restrict__ loss_parts) {
    const int t  = blockIdx.x * 256 + threadIdx.x;
    const float zv = z[t];
    const int sp = t & (SPAT - 1);
    const int c  = (t >> 13) & 255;
    const int b  = t >> 21;
    const int n  = (b << 13) + sp;
    const int id = idx[n];
    const float e    = W[id * EDIM + c];
    const float diff = e - zv;
    zq_out[t] = zv + diff;
    z_out[t]  = zv;

    double ds = (double)(diff * diff);
    #pragma unroll
    for (int off = 32; off > 0; off >>= 1) ds += __shfl_down(ds, off);
    __shared__ double bsum[4];
    const int lane = threadIdx.x & 63, w = threadIdx.x >> 6;
    if (lane == 0) bsum[w] = ds;
    __syncthreads();
    if (threadIdx.x == 0)
        loss_parts[blockIdx.x] = bsum[0] + bsum[1] + bsum[2] + bsum[3];
}

// ---------------------------------------------------------------------------
// K4: perplexity (from ghist, identical c-mapping/order) + loss finalize.
// ---------------------------------------------------------------------------
__global__ __launch_bounds__(1024) void final_kernel(
        const int* __restrict__ ghist, const double* __restrict__ loss_parts,
        float* __restrict__ out_loss, float* __restrict__ out_perp) {
    __shared__ float ps[1024];
    __shared__ double ls[1024];
    const int tid = threadIdx.x;

    float s = 0.f;
    for (int c = tid; c < N_E; c += 1024) {
        const float p = (float)ghist[c] * (1.0f / (float)NROWS);
        s += p * logf(p + 1e-10f);
    }
    double l = 0.0;
    for (int c = tid; c < NLOSSPARTS; c += 1024) l += loss_parts[c];
    ps[tid] = s;
    ls[tid] = l;
    __syncthreads();
    for (int off = 512; off > 0; off >>= 1) {
        if (tid < off) {
            ps[tid] += ps[tid + off];
            ls[tid] += ls[tid + off];
        }
        __syncthreads();
    }
    if (tid == 0) {
        *out_perp = expf(-ps[0]);
        const float m = (float)(ls[0] / (double)ZELEMS);
        *out_loss = m + 0.25f * m;
    }
}

// ---------------------------------------------------------------------------
extern "C" void kernel_launch(void* const* d_in, const int* in_sizes, int n_in,
                              void* d_out, int out_size, void* d_ws, size_t ws_size,
                              hipStream_t stream) {
    const float* z   = (const float*)d_in[0];
    const float* W   = (const float*)d_in[1];
    const float* ema = (const float*)d_in[2];
    float* out = (float*)d_out;

    float* out_loss   = out + OFF_LOSS;
    float* out_zq     = out + OFF_ZQ;
    float* out_perp   = out + OFF_PERP;
    float* out_onehot = out + OFF_ONEHOT;
    float* out_idx    = out + OFF_IDX;
    float* out_z      = out + OFF_ZOUT;
    float* out_ema    = out + OFF_EMA;

    // scratch inside later-overwritten output regions (16B-aligned bases)
    u16*   wh  = (u16*)(out + SCR_WH_F);
    int*   bI  = (int*)(out + SCR_BI_F);
    float* bDD = out + SCR_BDD_F;
    u16*   zh  = (u16*)(out + SCR_ZH_F);

    // workspace
    char* ws = (char*)d_ws;
    float*  se    = (float*)ws;                   // 16 KB
    float*  sz    = (float*)(ws + 16384);         // 64 KB
    int*    idxb  = (int*)  (ws + 81920);         // 64 KB
    double* lossp = (double*)(ws + 147456);       // 128 KB
    int*    ghist = (int*)  (ws + 278528);        // 16 KB

    prep_all_kernel<<<PB_TOT, 256, 0, stream>>>(W, ema, z, wh, se, out_ema,
                                                zh, sz, ghist);
    argmin_kernel<<<dim3(NROWS / 128, NCHUNK), 256, 0, stream>>>(
        zh, wh, se, sz, bDD, bI, out_onehot);
    resolve_kernel<<<NROWS, 128, 0, stream>>>(z, W, se, sz, bDD, bI,
                                              idxb, out_idx, out_onehot);
    hist_kernel<<<16, 1024, 0, stream>>>(idxb, ghist);
    outputs_kernel<<<ZELEMS / 256, 256, 0, stream>>>(z, W, idxb, out_zq, out_z,
                                                     lossp);
    final_kernel<<<1, 1024, 0, stream>>>(ghist, lossp, out_loss, out_perp);
}

// Round 12
// 459.742 us; speedup vs baseline: 1.2002x; 1.1271x over previous
//
#include <hip/hip_runtime.h>
#include <math.h>

// ---------------------------------------------------------------------------
// VectorQuantizer3D — R20: restructure resolve's slow path (R19 confirmed it
// as the dominant lever: ~2.1us per %-slow-path).
// (1) Sharper sound classification per chunk using stored (d1,d2):
//       d1 > thr          -> excluded (as before)
//       d1 <= thr < d2    -> ONLY candidate is stored i1 (1-code exact compute
//                            instead of 128-code rescan; any other code has
//                            q_mfma >= d2 > thr)
//       d2 <= thr         -> full rescan (3rd-best unbounded; ~2% of rows)
//     Candidate coverage identical to R19 -> bit-identical indices.
//     Generalized fast path (ncand==1 && no full chunks) == R19's gap test.
// (2) zt (transposed fp32 z, ws_size-gated, fallback to strided): slow row's
//     z-load becomes 1KB coalesced instead of 256 scattered lines.
// Everything else byte-identical to R19 (absmax 0.0, MARG/GAPM 1.3e-4).
// ---------------------------------------------------------------------------

#define N_E    4096
#define EDIM   256
#define SPAT   8192
#define NROWS  16384
#define ZELEMS 4194304
#define NCHUNK 32        // code chunks of 128
#define NLOSSPARTS 16384

// Output offsets (flat float32 in return order)
#define OFF_LOSS    0
#define OFF_ZQ      1
#define OFF_PERP    4194305
#define OFF_ONEHOT  4194306
#define OFF_IDX     71303170
#define OFF_ZOUT    71319554
#define OFF_EMA     75513858

// Scratch (float indices into out), all bases 16B-aligned, in regions
// rewritten by outputs_kernel AFTER their last scratch read:
//   out_zq region [1, 4194305):         wh [4,524292)
//   out_z  region [71319554, 75513858): bI [71319556,71843844),
//                                       bDD [71843844,72892420),
//                                       zh [72892420,74989572)
#define SCR_WH_F   4
#define SCR_BI_F   71319556
#define SCR_BDD_F  71843844
#define SCR_ZH_F   72892420

// zt (transposed fp32 z) in d_ws, runtime-gated on ws_size
#define ZT_OFF     294912
#define ZT_BYTES   16777216

// 1-product error budget at 1.3e-4: |q_mfma - q_r6| <= 2|dm| + ulp(512)
// (3.05e-5); dm = sum(z_lo*wh + zh*wl), sigma ~2.8e-6 -> 18-sigma budget,
// 2.9x expected max over 6.7e7 trials. Validated absmax 0.0 in R19.
#define MARG 1.3e-4f

// prep_all blockIdx ranges
#define PB_W0   0        // 1024 blocks: W split + ema + se
#define PB_Z0   1024     // 512 blocks: split_z
#define PB_N0   1536     // 128 blocks: rnorm
#define PB_H0   1664     // 4 blocks: ghist zero
#define PB_TOT  1668

typedef unsigned short u16;
typedef short short8 __attribute__((ext_vector_type(8)));
typedef float f32x4 __attribute__((ext_vector_type(4)));
typedef const void __attribute__((address_space(1)))* gas1;
typedef void __attribute__((address_space(3)))* las3;
#define GLOAD16(g, l) __builtin_amdgcn_global_load_lds((gas1)(g), (las3)(l), 16, 0, 0)

__device__ __forceinline__ u16 f2bf(float f) {   // RTNE fp32 -> bf16
    unsigned u = __float_as_uint(f);
    return (u16)((u + 0x7fffu + ((u >> 16) & 1u)) >> 16);
}
__device__ __forceinline__ float bf2f(u16 h) {
    return __uint_as_float(((unsigned)h) << 16);
}

// ---------------------------------------------------------------------------
// K0: prep_all — fused {W split(hi) + ema + se} | split_z(+zt) | rnorm | hist0
// ---------------------------------------------------------------------------
__global__ __launch_bounds__(256) void prep_all_kernel(
        const float* __restrict__ W, const float* __restrict__ ema,
        const float* __restrict__ z,
        u16* __restrict__ wh,
        float* __restrict__ se, float* __restrict__ out_ema,
        u16* __restrict__ zh, float* __restrict__ sz,
        int* __restrict__ ghist, float* __restrict__ zt) {
    __shared__ float t[128][65];       // split_z transpose tile
    __shared__ float szp[4][128];      // rnorm partials
    const int bx  = blockIdx.x;
    const int tid = threadIdx.x;

    if (bx < PB_Z0) {
        // ---- W prep: split(hi) + ema + se (VERBATIM R6 se numerics) ----
        const size_t tt = (size_t)bx * 256 + tid;       // 0..262143
        const int code = (int)(tt >> 6);
        const int lane = tid & 63;
        const float4 v = *(const float4*)(W + tt * 4);

        u16 h0 = f2bf(v.x), h1 = f2bf(v.y), h2 = f2bf(v.z), h3 = f2bf(v.w);
        uint2 hp;
        hp.x = (unsigned)h0 | ((unsigned)h1 << 16); hp.y = (unsigned)h2 | ((unsigned)h3 << 16);
        *(uint2*)(wh + tt * 4) = hp;

        const float4 e4 = *(const float4*)(ema + tt * 4);
        float4 o4;
        o4.x = 0.25f * e4.x + 0.75f * v.x;
        o4.y = 0.25f * e4.y + 0.75f * v.y;
        o4.z = 0.25f * e4.z + 0.75f * v.z;
        o4.w = 0.25f * e4.w + 0.75f * v.w;
        *(float4*)(out_ema + tt * 4) = o4;

        float s = v.x * v.x + v.y * v.y + v.z * v.z + v.w * v.w;
        #pragma unroll
        for (int off = 32; off > 0; off >>= 1) s += __shfl_down(s, off);
        if (lane == 0) se[code] = s;
    } else if (bx < PB_N0) {
        // ---- split_z: transposed bf16 hi [16384 rows][256 k] (+ fp32 zt) ----
        const int sub = bx - PB_Z0;
        const int sp0 = (sub & 127) * 64, c0 = ((sub >> 7) & 1) * 128, b = sub >> 8;
        const int wid = tid >> 6, lane = tid & 63;
        const float* zb = z + (size_t)b * (EDIM * SPAT);
        #pragma unroll
        for (int it = 0; it < 32; ++it) {
            const int cl = wid + 4 * it;                 // 0..127
            t[cl][lane] = zb[(size_t)(c0 + cl) * SPAT + sp0 + lane];
        }
        __syncthreads();
        #pragma unroll
        for (int it = 0; it < 16; ++it) {
            const int r = wid + 4 * it;                  // 0..63
            const float v0 = t[2 * lane][r], v1 = t[2 * lane + 1][r];
            const u16 h0 = f2bf(v0), h1 = f2bf(v1);
            const size_t row = (size_t)b * SPAT + sp0 + r;
            ((unsigned*)zh)[row * 128 + (c0 >> 1) + lane] = (unsigned)h0 | ((unsigned)h1 << 16);
            if (zt) {
                float2 p; p.x = v0; p.y = v1;
                *(float2*)(zt + row * 256 + c0 + 2 * lane) = p;
            }
        }
    } else if (bx < PB_H0) {
        // ---- rnorm (R6 exact order; 256-thread variant, identical partials)
        const int r0 = (bx - PB_N0) * 128;
        const int bb = r0 >> 13;
        const int sp0 = r0 & (SPAT - 1);
        const float* zb = z + (size_t)bb * (EDIM * SPAT) + sp0;
        const int lr = tid & 127, kh = tid >> 7;         // kh 0..1
        #pragma unroll
        for (int h = 0; h < 2; ++h) {
            const int kq = kh * 2 + h;                   // covers 0..3
            float s = 0.f;
            const float* p = zb + lr + (size_t)(kq * 64) * SPAT;
            for (int k = 0; k < 64; ++k) {
                float v = p[(size_t)k * SPAT];
                s += v * v;
            }
            szp[kq][lr] = s;
        }
        __syncthreads();
        if (tid < 128)
            sz[r0 + tid] = ((szp[0][tid] + szp[1][tid]) + szp[2][tid]) + szp[3][tid];
    } else {
        // ---- ghist zero: 4 blocks x 1024 entries ----
        const int base = (bx - PB_H0) * 1024;
        #pragma unroll
        for (int j = 0; j < 4; ++j) ghist[base + j * 256 + tid] = 0;
    }
}

// ---------------------------------------------------------------------------
// K1: 1-product MFMA argmin + per-chunk top-2 + one-hot zero slice.
// (byte-identical to R19)
// ---------------------------------------------------------------------------
__global__ __launch_bounds__(256, 4) void argmin_kernel(
        const u16* __restrict__ zh, const u16* __restrict__ wh,
        const float* __restrict__ se, const float* __restrict__ sz,
        float* __restrict__ bDD, int* __restrict__ bI,
        float* __restrict__ out_onehot) {
    __shared__ u16 sW[2][128][32];  // 16 KB: [buf][code][hi32]
    __shared__ u16 sZ[2][128][32];  // 16 KB: [buf][row ][hi32]
    __shared__ float mD[2][128];
    __shared__ int   mI[2][128];
    __shared__ float mD2[2][128];

    const int tid = threadIdx.x;
    const int wid = tid >> 6, lane = tid & 63;
    const int wm = wid >> 1, wn = wid & 1;
    const int lq = lane >> 4, lr = lane & 15;
    const int chunk = blockIdx.y;          // 0..31
    const int rbase = blockIdx.x * 128;
    const int cbase = chunk * 128;

    const u16* gw[2]; const u16* gz[2];
    #pragma unroll
    for (int j = 0; j < 2; ++j) {
        const int o = j * 256 + tid;
        const int row = o >> 2, g = o & 3, u = g ^ ((row >> 1) & 3);
        gw[j] = wh + (size_t)(cbase + row) * EDIM + u * 8;
        gz[j] = zh + (size_t)(rbase + row) * EDIM + u * 8;
    }

    char* sWb = (char*)&sW[0][0][0];
    char* sZb = (char*)&sZ[0][0][0];

    int aoff[4], boff[4];
    #pragma unroll
    for (int tt = 0; tt < 4; ++tt) {
        const int cl = wn * 64 + tt * 16 + lr;
        aoff[tt] = cl * 64 + (lq ^ ((cl >> 1) & 3)) * 16;
        const int rl = wm * 64 + tt * 16 + lr;
        boff[tt] = rl * 64 + (lq ^ ((rl >> 1) & 3)) * 16;
    }

    f32x4 acc[4][4];
    #pragma unroll
    for (int ci = 0; ci < 4; ++ci)
        #pragma unroll
        for (int rj = 0; rj < 4; ++rj) {
            f32x4 zzz = {0.f, 0.f, 0.f, 0.f};
            acc[ci][rj] = zzz;
        }

    #define STAGE(b) do {                                                      \
        _Pragma("unroll")                                                      \
        for (int j = 0; j < 2; ++j) {                                          \
            GLOAD16(gw[j], sWb + (b) * 8192 + (j * 256 + wid * 64) * 16);      \
            GLOAD16(gz[j], sZb + (b) * 8192 + (j * 256 + wid * 64) * 16);      \
            gw[j] += 32; gz[j] += 32;                                          \
        }                                                                      \
    } while (0)

    STAGE(0);
    __syncthreads();                       // drain prologue -> buf0 ready

    for (int k0 = 0; k0 < 8; ++k0) {
        const int cur = k0 & 1;
        if (k0 < 7) STAGE(cur ^ 1);        // next tile in flight during compute

        const char* wbase = sWb + cur * 8192;
        const char* zbase = sZb + cur * 8192;
        short8 zb[4];
        #pragma unroll
        for (int rj = 0; rj < 4; ++rj)
            zb[rj] = *(const short8*)(zbase + boff[rj]);
        #pragma unroll
        for (int ci = 0; ci < 4; ++ci) {
            const short8 wah = *(const short8*)(wbase + aoff[ci]);
            #pragma unroll
            for (int rj = 0; rj < 4; ++rj)
                acc[ci][rj] = __builtin_amdgcn_mfma_f32_16x16x32_bf16(wah, zb[rj], acc[ci][rj], 0, 0, 0);
        }
        __syncthreads();                   // drains next-tile loads + read fence
    }
    #undef STAGE

    // ---- epilogue: per-chunk quantized top-2 (value-only second) ----
    f32x4 sev[4];
    #pragma unroll
    for (int ci = 0; ci < 4; ++ci)
        sev[ci] = *(const f32x4*)(se + cbase + wn * 64 + ci * 16 + lq * 4);

    #pragma unroll
    for (int rj = 0; rj < 4; ++rj) {
        const int rloc = wm * 64 + rj * 16 + lr;
        const float szr = sz[rbase + rloc];
        float b1 = 3.4e38f, b2 = 3.4e38f; int bi1 = 0x7fffffff;
        #pragma unroll
        for (int ci = 0; ci < 4; ++ci) {
            #pragma unroll
            for (int r = 0; r < 4; ++r) {
                const float q = (szr + sev[ci][r]) - 2.0f * acc[ci][rj][r];
                const int code = cbase + wn * 64 + ci * 16 + lq * 4 + r;
                if (q < b1 || (q == b1 && code < bi1)) {
                    b2 = b1; b1 = q; bi1 = code;
                } else if (q < b2) {
                    b2 = q;
                }
            }
        }
        #pragma unroll
        for (int mask = 16; mask <= 32; mask <<= 1) {
            const float od1 = __shfl_xor(b1, mask);
            const int   oi1 = __shfl_xor(bi1, mask);
            const float od2 = __shfl_xor(b2, mask);
            const bool ot = (od1 < b1) || (od1 == b1 && oi1 < bi1);
            if (ot) { b2 = fminf(b1, od2); b1 = od1; bi1 = oi1; }
            else    { b2 = fminf(b2, od1); }
        }
        if (lq == 0) {
            mD[wn][rloc]  = b1;
            mI[wn][rloc]  = bi1;
            mD2[wn][rloc] = b2;
        }
    }
    __syncthreads();
    if (tid < 128) {
        const float d0 = mD[0][tid], d1 = mD[1][tid];
        const int   i0 = mI[0][tid], i1 = mI[1][tid];
        const float s0 = mD2[0][tid], s1 = mD2[1][tid];
        float dm, sm; int im;
        if (d1 < d0 || (d1 == d0 && i1 < i0)) { dm = d1; im = i1; sm = fminf(s1, d0); }
        else                                  { dm = d0; im = i0; sm = fminf(s0, d1); }
        const int row = rbase + tid;
        float2 p; p.x = dm; p.y = sm;
        *(float2*)(bDD + (size_t)row * 64 + chunk * 2) = p;
        bI[(size_t)row * 32 + chunk] = im;
    }

    // ---- one-hot zero slice (64 KB per block; drains under block exit) ----
    {
        const int slice = blockIdx.x * 32 + blockIdx.y;   // 0..4095, bijective
        float* oh = out_onehot + (size_t)slice * 16384;
        const float4 z4 = {0.f, 0.f, 0.f, 0.f};
        #pragma unroll
        for (int it = 0; it < 16; ++it)
            *(float4*)(oh + it * 1024 + tid * 4) = z4;
    }
}

// ---------------------------------------------------------------------------
// K1b: resolve — sharp candidate classification.
// thr = g1 + MARG. Per chunk: d1>thr -> skip; d1<=thr<d2 -> candidate {i1};
// d2<=thr -> full rescan. Unique candidate + no full chunks -> accept (==
// R19's fast path). Candidate coverage identical to R19 -> same indices.
// ---------------------------------------------------------------------------
__global__ __launch_bounds__(128) void resolve_kernel(
        const float* __restrict__ z, const float* __restrict__ W,
        const float* __restrict__ se, const float* __restrict__ sz,
        const float* __restrict__ bDD, const int* __restrict__ bI,
        const float* __restrict__ zt,
        int* __restrict__ idx_ws, float* __restrict__ out_idx,
        float* __restrict__ out_onehot) {
    __shared__ float zr[EDIM];
    __shared__ float rd[128];
    __shared__ int   ri[128];
    __shared__ int   scode[32];
    __shared__ unsigned sfull;
    __shared__ int   sncand;
    const int row = blockIdx.x;
    const int tid = threadIdx.x;

    if (tid < 64) {
        const int c = tid & 31;
        const float2 dd = *(const float2*)(bDD + (size_t)row * 64 + c * 2);
        float g1 = dd.x;
        #pragma unroll
        for (int mask = 16; mask > 0; mask >>= 1)
            g1 = fminf(g1, __shfl_xor(g1, mask));
        const float thr = g1 + MARG;
        const unsigned long long mful = __ballot(dd.y <= thr);
        const unsigned long long mcnd = __ballot(dd.x <= thr && dd.y > thr);
        const unsigned fm = (unsigned)(mful & 0xffffffffu);
        const unsigned cm = (unsigned)(mcnd & 0xffffffffu);
        if (tid < 32 && ((cm >> tid) & 1u)) {
            const int pos = __popc(cm & ((1u << tid) - 1u));
            scode[pos] = bI[(size_t)row * 32 + tid];
        }
        if (tid == 0) { sfull = fm; sncand = __popc(cm); }
    }
    __syncthreads();

    const unsigned fmask = sfull;
    const int ncand = sncand;

    if (fmask == 0u && ncand == 1) {       // unique candidate -> winner
        if (tid == 0) {
            const int ii = scode[0];
            idx_ws[row]  = ii;
            out_idx[row] = (float)ii;
            out_onehot[(size_t)row * N_E + ii] = 1.0f;
        }
        return;
    }

    // exact distances needed: load z row (coalesced via zt when available)
    if (zt) {
        zr[tid]       = zt[(size_t)row * EDIM + tid];
        zr[tid + 128] = zt[(size_t)row * EDIM + tid + 128];
    } else {
        const int b = row >> 13, sp = row & (SPAT - 1);
        zr[tid]       = z[(size_t)b * (EDIM * SPAT) + (size_t)tid * SPAT + sp];
        zr[tid + 128] = z[(size_t)b * (EDIM * SPAT) + (size_t)(tid + 128) * SPAT + sp];
    }
    __syncthreads();

    const float szr = sz[row];
    float best = 3.4e38f; int bi = 0x7fffffff;

    // (a) single-code exact computes (R6-exact serial-k), thread t = cand t
    if (tid < ncand) {
        const int code = scode[tid];
        const float* wr = W + (size_t)code * EDIM;
        float s = 0.f;
        for (int k = 0; k < EDIM; ++k) s += zr[k] * wr[k];   // serial k
        const float q = (szr + se[code]) - 2.0f * s;
        if (q < best || (q == best && code < bi)) { best = q; bi = code; }
    }
    // (b) full-chunk rescans (rare: chunk's 2nd-best within thr)
    unsigned cmask = fmask;
    while (cmask) {
        const int cc = __ffs(cmask) - 1;
        cmask &= cmask - 1;
        const int code = cc * 128 + tid;
        const float* wr = W + (size_t)code * EDIM;
        float s = 0.f;
        for (int k = 0; k < EDIM; ++k) s += zr[k] * wr[k];   // serial k
        const float q = (szr + se[code]) - 2.0f * s;
        if (q < best || (q == best && code < bi)) { best = q; bi = code; }
    }
    rd[tid] = best; ri[tid] = bi;
    __syncthreads();
    for (int off = 64; off > 0; off >>= 1) {
        if (tid < off) {
            const float od = rd[tid + off]; const int oi = ri[tid + off];
            if (od < rd[tid] || (od == rd[tid] && oi < ri[tid])) {
                rd[tid] = od; ri[tid] = oi;
            }
        }
        __syncthreads();
    }
    if (tid == 0) {
        const int ii = ri[0];
        idx_ws[row]  = ii;
        out_idx[row] = (float)ii;
        out_onehot[(size_t)row * N_E + ii] = 1.0f;
    }
}

// ---------------------------------------------------------------------------
// K1c: hist — 16 blocks x 1024 rows, private LDS histogram + global merge.
// ---------------------------------------------------------------------------
__global__ __launch_bounds__(1024) void hist_kernel(const int* __restrict__ idx,
                                                    int* __restrict__ ghist) {
    __shared__ int lh[N_E];
    const int tid = threadIdx.x;
    for (int i = tid; i < N_E; i += 1024) lh[i] = 0;
    __syncthreads();
    atomicAdd(&lh[idx[blockIdx.x * 1024 + tid]], 1);
    __syncthreads();
    for (int c = tid; c < N_E; c += 1024) {
        const int v = lh[c];
        if (v) atomicAdd(&ghist[c], v);
    }
}

// ---------------------------------------------------------------------------
// K2: z_q_out, z_out, loss partials — unchanged from R6.
// ---------------------------------------------------------------------------
__global__ __launch_bounds__(256) void outputs_kernel(
        const float* __restrict__ z, const float* __restrict__ W,
        const int* __restrict__ idx,
        float* __restrict__ zq_out, float* __restrict__ z_out,
        double* __restrict__ loss_parts) {
    const int t  = blockIdx.x * 256 + threadIdx.x;
    const float zv = z[t];
    const int sp = t & (SPAT - 1);
    const int c  = (t >> 13) & 255;
    const int b  = t >> 21;
    const int n  = (b << 13) + sp;
    const int id = idx[n];
    const float e    = W[id * EDIM + c];
    const float diff = e - zv;
    zq_out[t] = zv + diff;
    z_out[t]  = zv;

    double ds = (double)(diff * diff);
    #pragma unroll
    for (int off = 32; off > 0; off >>= 1) ds += __shfl_down(ds, off);
    __shared__ double bsum[4];
    const int lane = threadIdx.x & 63, w = threadIdx.x >> 6;
    if (lane == 0) bsum[w] = ds;
    __syncthreads();
    if (threadIdx.x == 0)
        loss_parts[blockIdx.x] = bsum[0] + bsum[1] + bsum[2] + bsum[3];
}

// ---------------------------------------------------------------------------
// K4: perplexity (from ghist, identical c-mapping/order) + loss finalize.
// ---------------------------------------------------------------------------
__global__ __launch_bounds__(1024) void final_kernel(
        const int* __restrict__ ghist, const double* __restrict__ loss_parts,
        float* __restrict__ out_loss, float* __restrict__ out_perp) {
    __shared__ float ps[1024];
    __shared__ double ls[1024];
    const int tid = threadIdx.x;

    float s = 0.f;
    for (int c = tid; c < N_E; c += 1024) {
        const float p = (float)ghist[c] * (1.0f / (float)NROWS);
        s += p * logf(p + 1e-10f);
    }
    double l = 0.0;
    for (int c = tid; c < NLOSSPARTS; c += 1024) l += loss_parts[c];
    ps[tid] = s;
    ls[tid] = l;
    __syncthreads();
    for (int off = 512; off > 0; off >>= 1) {
        if (tid < off) {
            ps[tid] += ps[tid + off];
            ls[tid] += ls[tid + off];
        }
        __syncthreads();
    }
    if (tid == 0) {
        *out_perp = expf(-ps[0]);
        const float m = (float)(ls[0] / (double)ZELEMS);
        *out_loss = m + 0.25f * m;
    }
}

// ---------------------------------------------------------------------------
extern "C" void kernel_launch(void* const* d_in, const int* in_sizes, int n_in,
                              void* d_out, int out_size, void* d_ws, size_t ws_size,
                              hipStream_t stream) {
    const float* z   = (const float*)d_in[0];
    const float* W   = (const float*)d_in[1];
    const float* ema = (const float*)d_in[2];
    float* out = (float*)d_out;

    float* out_loss   = out + OFF_LOSS;
    float* out_zq     = out + OFF_ZQ;
    float* out_perp   = out + OFF_PERP;
    float* out_onehot = out + OFF_ONEHOT;
    float* out_idx    = out + OFF_IDX;
    float* out_z      = out + OFF_ZOUT;
    float* out_ema    = out + OFF_EMA;

    // scratch inside later-overwritten output regions (16B-aligned bases)
    u16*   wh  = (u16*)(out + SCR_WH_F);
    int*   bI  = (int*)(out + SCR_BI_F);
    float* bDD = out + SCR_BDD_F;
    u16*   zh  = (u16*)(out + SCR_ZH_F);

    // workspace
    char* ws = (char*)d_ws;
    float*  se    = (float*)ws;                   // 16 KB
    float*  sz    = (float*)(ws + 16384);         // 64 KB
    int*    idxb  = (int*)  (ws + 81920);         // 64 KB
    double* lossp = (double*)(ws + 147456);       // 128 KB
    int*    ghist = (int*)  (ws + 278528);        // 16 KB
    float*  zt    = (ws_size >= (size_t)ZT_OFF + ZT_BYTES)
                        ? (float*)(ws + ZT_OFF) : (float*)0;  // 16 MB, optional

    prep_all_kernel<<<PB_TOT, 256, 0, stream>>>(W, ema, z, wh, se, out_ema,
                                                zh, sz, ghist, zt);
    argmin_kernel<<<dim3(NROWS / 128, NCHUNK), 256, 0, stream>>>(
        zh, wh, se, sz, bDD, bI, out_onehot);
    resolve_kernel<<<NROWS, 128, 0, stream>>>(z, W, se, sz, bDD, bI, zt,
                                              idxb, out_idx, out_onehot);
    hist_kernel<<<16, 1024, 0, stream>>>(idxb, ghist);
    outputs_kernel<<<ZELEMS / 256, 256, 0, stream>>>(z, W, idxb, out_zq, out_z,
                                                     lossp);
    final_kernel<<<1, 1024, 0, stream>>>(ghist, lossp, out_loss, out_perp);
}

// Round 15
// 445.421 us; speedup vs baseline: 1.2387x; 1.0322x over previous
//
#include <hip/hip_runtime.h>
#include <math.h>

// ---------------------------------------------------------------------------
// VectorQuantizer3D — R23 (= R21/R22 with the nt-store COMPILE FIX:
// __builtin_nontemporal_store requires clang ext_vector_type, not
// HIP_vector_type float4/float2 — R13/R14 "failures" were this).
// nontemporal (streaming) stores for all write-once outputs: one-hot zeros
// (268 MB), zq/z_out (34 MB), zt (64 MB), ema (4 MB). Mechanism: these
// streams thrash the 4 MB/XCD L2 that argmin's wh/zh re-reads (128x/32x)
// and outputs' W gathers depend on. nt marks them early-evict; values
// bitwise identical. Re-read scratch (zh, bDD, bI, wh) stays cached.
// Everything else byte-identical to R20 (459.7us, absmax 0.0).
// ---------------------------------------------------------------------------

#define N_E    4096
#define EDIM   256
#define SPAT   8192
#define NROWS  16384
#define ZELEMS 4194304
#define NCHUNK 32        // code chunks of 128
#define NLOSSPARTS 16384

// Output offsets (flat float32 in return order)
#define OFF_LOSS    0
#define OFF_ZQ      1
#define OFF_PERP    4194305
#define OFF_ONEHOT  4194306
#define OFF_IDX     71303170
#define OFF_ZOUT    71319554
#define OFF_EMA     75513858

// Scratch (float indices into out), all bases 16B-aligned, in regions
// rewritten by outputs_kernel AFTER their last scratch read:
//   out_zq region [1, 4194305):         wh [4,524292)
//   out_z  region [71319554, 75513858): bI [71319556,71843844),
//                                       bDD [71843844,72892420),
//                                       zh [72892420,74989572)
#define SCR_WH_F   4
#define SCR_BI_F   71319556
#define SCR_BDD_F  71843844
#define SCR_ZH_F   72892420

// zt (transposed fp32 z) in d_ws, runtime-gated on ws_size
#define ZT_OFF     294912
#define ZT_BYTES   16777216

// 1-product error budget at 1.3e-4: |q_mfma - q_r6| <= 2|dm| + ulp(512)
// (3.05e-5); dm = sum(z_lo*wh + zh*wl), sigma ~2.8e-6 -> 18-sigma budget,
// 2.9x expected max over 6.7e7 trials. Validated absmax 0.0 in R19/R20.
#define MARG 1.3e-4f

// prep_all blockIdx ranges
#define PB_W0   0        // 1024 blocks: W split + ema + se
#define PB_Z0   1024     // 512 blocks: split_z
#define PB_N0   1536     // 128 blocks: rnorm
#define PB_H0   1664     // 4 blocks: ghist zero
#define PB_TOT  1668

typedef unsigned short u16;
typedef short short8 __attribute__((ext_vector_type(8)));
typedef float f32x4 __attribute__((ext_vector_type(4)));
typedef float f32x2 __attribute__((ext_vector_type(2)));
typedef const void __attribute__((address_space(1)))* gas1;
typedef void __attribute__((address_space(3)))* las3;
#define GLOAD16(g, l) __builtin_amdgcn_global_load_lds((gas1)(g), (las3)(l), 16, 0, 0)

// nt stores via clang ext vectors (builtin rejects HIP_vector_type)
__device__ __forceinline__ void nt_store4(float* p, float a, float b, float c, float d) {
    f32x4 v = {a, b, c, d};
    __builtin_nontemporal_store(v, (f32x4*)p);
}
__device__ __forceinline__ void nt_store2(float* p, float a, float b) {
    f32x2 v = {a, b};
    __builtin_nontemporal_store(v, (f32x2*)p);
}
__device__ __forceinline__ void nt_store1(float* p, float a) {
    __builtin_nontemporal_store(a, p);
}

__device__ __forceinline__ u16 f2bf(float f) {   // RTNE fp32 -> bf16
    unsigned u = __float_as_uint(f);
    return (u16)((u + 0x7fffu + ((u >> 16) & 1u)) >> 16);
}
__device__ __forceinline__ float bf2f(u16 h) {
    return __uint_as_float(((unsigned)h) << 16);
}

// ---------------------------------------------------------------------------
// K0: prep_all — fused {W split(hi) + ema + se} | split_z(+zt) | rnorm | hist0
// ---------------------------------------------------------------------------
__global__ __launch_bounds__(256) void prep_all_kernel(
        const float* __restrict__ W, const float* __restrict__ ema,
        const float* __restrict__ z,
        u16* __restrict__ wh,
        float* __restrict__ se, float* __restrict__ out_ema,
        u16* __restrict__ zh, float* __restrict__ sz,
        int* __restrict__ ghist, float* __restrict__ zt) {
    __shared__ float t[128][65];       // split_z transpose tile
    __shared__ float szp[4][128];      // rnorm partials
    const int bx  = blockIdx.x;
    const int tid = threadIdx.x;

    if (bx < PB_Z0) {
        // ---- W prep: split(hi) + ema + se (VERBATIM R6 se numerics) ----
        const size_t tt = (size_t)bx * 256 + tid;       // 0..262143
        const int code = (int)(tt >> 6);
        const int lane = tid & 63;
        const float4 v = *(const float4*)(W + tt * 4);

        u16 h0 = f2bf(v.x), h1 = f2bf(v.y), h2 = f2bf(v.z), h3 = f2bf(v.w);
        uint2 hp;
        hp.x = (unsigned)h0 | ((unsigned)h1 << 16); hp.y = (unsigned)h2 | ((unsigned)h3 << 16);
        *(uint2*)(wh + tt * 4) = hp;

        const float4 e4 = *(const float4*)(ema + tt * 4);
        nt_store4(out_ema + tt * 4,
                  0.25f * e4.x + 0.75f * v.x,
                  0.25f * e4.y + 0.75f * v.y,
                  0.25f * e4.z + 0.75f * v.z,
                  0.25f * e4.w + 0.75f * v.w);

        float s = v.x * v.x + v.y * v.y + v.z * v.z + v.w * v.w;
        #pragma unroll
        for (int off = 32; off > 0; off >>= 1) s += __shfl_down(s, off);
        if (lane == 0) se[code] = s;
    } else if (bx < PB_N0) {
        // ---- split_z: transposed bf16 hi [16384 rows][256 k] (+ fp32 zt) ----
        const int sub = bx - PB_Z0;
        const int sp0 = (sub & 127) * 64, c0 = ((sub >> 7) & 1) * 128, b = sub >> 8;
        const int wid = tid >> 6, lane = tid & 63;
        const float* zb = z + (size_t)b * (EDIM * SPAT);
        #pragma unroll
        for (int it = 0; it < 32; ++it) {
            const int cl = wid + 4 * it;                 // 0..127
            t[cl][lane] = zb[(size_t)(c0 + cl) * SPAT + sp0 + lane];
        }
        __syncthreads();
        #pragma unroll
        for (int it = 0; it < 16; ++it) {
            const int r = wid + 4 * it;                  // 0..63
            const float v0 = t[2 * lane][r], v1 = t[2 * lane + 1][r];
            const u16 h0 = f2bf(v0), h1 = f2bf(v1);
            const size_t row = (size_t)b * SPAT + sp0 + r;
            ((unsigned*)zh)[row * 128 + (c0 >> 1) + lane] = (unsigned)h0 | ((unsigned)h1 << 16);
            if (zt) nt_store2(zt + row * 256 + c0 + 2 * lane, v0, v1);
        }
    } else if (bx < PB_H0) {
        // ---- rnorm (R6 exact order; 256-thread variant, identical partials)
        const int r0 = (bx - PB_N0) * 128;
        const int bb = r0 >> 13;
        const int sp0 = r0 & (SPAT - 1);
        const float* zb = z + (size_t)bb * (EDIM * SPAT) + sp0;
        const int lr = tid & 127, kh = tid >> 7;         // kh 0..1
        #pragma unroll
        for (int h = 0; h < 2; ++h) {
            const int kq = kh * 2 + h;                   // covers 0..3
            float s = 0.f;
            const float* p = zb + lr + (size_t)(kq * 64) * SPAT;
            for (int k = 0; k < 64; ++k) {
                float v = p[(size_t)k * SPAT];
                s += v * v;
            }
            szp[kq][lr] = s;
        }
        __syncthreads();
        if (tid < 128)
            sz[r0 + tid] = ((szp[0][tid] + szp[1][tid]) + szp[2][tid]) + szp[3][tid];
    } else {
        // ---- ghist zero: 4 blocks x 1024 entries ----
        const int base = (bx - PB_H0) * 1024;
        #pragma unroll
        for (int j = 0; j < 4; ++j) ghist[base + j * 256 + tid] = 0;
    }
}

// ---------------------------------------------------------------------------
// K1: 1-product MFMA argmin + per-chunk top-2 + one-hot zero slice (nt).
// ---------------------------------------------------------------------------
__global__ __launch_bounds__(256, 4) void argmin_kernel(
        const u16* __restrict__ zh, const u16* __restrict__ wh,
        const float* __restrict__ se, const float* __restrict__ sz,
        float* __restrict__ bDD, int* __restrict__ bI,
        float* __restrict__ out_onehot) {
    __shared__ u16 sW[2][128][32];  // 16 KB: [buf][code][hi32]
    __shared__ u16 sZ[2][128][32];  // 16 KB: [buf][row ][hi32]
    __shared__ float mD[2][128];
    __shared__ int   mI[2][128];
    __shared__ float mD2[2][128];

    const int tid = threadIdx.x;
    const int wid = tid >> 6, lane = tid & 63;
    const int wm = wid >> 1, wn = wid & 1;
    const int lq = lane >> 4, lr = lane & 15;
    const int chunk = blockIdx.y;          // 0..31
    const int rbase = blockIdx.x * 128;
    const int cbase = chunk * 128;

    const u16* gw[2]; const u16* gz[2];
    #pragma unroll
    for (int j = 0; j < 2; ++j) {
        const int o = j * 256 + tid;
        const int row = o >> 2, g = o & 3, u = g ^ ((row >> 1) & 3);
        gw[j] = wh + (size_t)(cbase + row) * EDIM + u * 8;
        gz[j] = zh + (size_t)(rbase + row) * EDIM + u * 8;
    }

    char* sWb = (char*)&sW[0][0][0];
    char* sZb = (char*)&sZ[0][0][0];

    int aoff[4], boff[4];
    #pragma unroll
    for (int tt = 0; tt < 4; ++tt) {
        const int cl = wn * 64 + tt * 16 + lr;
        aoff[tt] = cl * 64 + (lq ^ ((cl >> 1) & 3)) * 16;
        const int rl = wm * 64 + tt * 16 + lr;
        boff[tt] = rl * 64 + (lq ^ ((rl >> 1) & 3)) * 16;
    }

    f32x4 acc[4][4];
    #pragma unroll
    for (int ci = 0; ci < 4; ++ci)
        #pragma unroll
        for (int rj = 0; rj < 4; ++rj) {
            f32x4 zzz = {0.f, 0.f, 0.f, 0.f};
            acc[ci][rj] = zzz;
        }

    #define STAGE(b) do {                                                      \
        _Pragma("unroll")                                                      \
        for (int j = 0; j < 2; ++j) {                                          \
            GLOAD16(gw[j], sWb + (b) * 8192 + (j * 256 + wid * 64) * 16);      \
            GLOAD16(gz[j], sZb + (b) * 8192 + (j * 256 + wid * 64) * 16);      \
            gw[j] += 32; gz[j] += 32;                                          \
        }                                                                      \
    } while (0)

    STAGE(0);
    __syncthreads();                       // drain prologue -> buf0 ready

    for (int k0 = 0; k0 < 8; ++k0) {
        const int cur = k0 & 1;
        if (k0 < 7) STAGE(cur ^ 1);        // next tile in flight during compute

        const char* wbase = sWb + cur * 8192;
        const char* zbase = sZb + cur * 8192;
        short8 zb[4];
        #pragma unroll
        for (int rj = 0; rj < 4; ++rj)
            zb[rj] = *(const short8*)(zbase + boff[rj]);
        #pragma unroll
        for (int ci = 0; ci < 4; ++ci) {
            const short8 wah = *(const short8*)(wbase + aoff[ci]);
            #pragma unroll
            for (int rj = 0; rj < 4; ++rj)
                acc[ci][rj] = __builtin_amdgcn_mfma_f32_16x16x32_bf16(wah, zb[rj], acc[ci][rj], 0, 0, 0);
        }
        __syncthreads();                   // drains next-tile loads + read fence
    }
    #undef STAGE

    // ---- epilogue: per-chunk quantized top-2 (value-only second) ----
    f32x4 sev[4];
    #pragma unroll
    for (int ci = 0; ci < 4; ++ci)
        sev[ci] = *(const f32x4*)(se + cbase + wn * 64 + ci * 16 + lq * 4);

    #pragma unroll
    for (int rj = 0; rj < 4; ++rj) {
        const int rloc = wm * 64 + rj * 16 + lr;
        const float szr = sz[rbase + rloc];
        float b1 = 3.4e38f, b2 = 3.4e38f; int bi1 = 0x7fffffff;
        #pragma unroll
        for (int ci = 0; ci < 4; ++ci) {
            #pragma unroll
            for (int r = 0; r < 4; ++r) {
                const float q = (szr + sev[ci][r]) - 2.0f * acc[ci][rj][r];
                const int code = cbase + wn * 64 + ci * 16 + lq * 4 + r;
                if (q < b1 || (q == b1 && code < bi1)) {
                    b2 = b1; b1 = q; bi1 = code;
                } else if (q < b2) {
                    b2 = q;
                }
            }
        }
        #pragma unroll
        for (int mask = 16; mask <= 32; mask <<= 1) {
            const float od1 = __shfl_xor(b1, mask);
            const int   oi1 = __shfl_xor(bi1, mask);
            const float od2 = __shfl_xor(b2, mask);
            const bool ot = (od1 < b1) || (od1 == b1 && oi1 < bi1);
            if (ot) { b2 = fminf(b1, od2); b1 = od1; bi1 = oi1; }
            else    { b2 = fminf(b2, od1); }
        }
        if (lq == 0) {
            mD[wn][rloc]  = b1;
            mI[wn][rloc]  = bi1;
            mD2[wn][rloc] = b2;
        }
    }
    __syncthreads();
    if (tid < 128) {
        const float d0 = mD[0][tid], d1 = mD[1][tid];
        const int   i0 = mI[0][tid], i1 = mI[1][tid];
        const float s0 = mD2[0][tid], s1 = mD2[1][tid];
        float dm, sm; int im;
        if (d1 < d0 || (d1 == d0 && i1 < i0)) { dm = d1; im = i1; sm = fminf(s1, d0); }
        else                                  { dm = d0; im = i0; sm = fminf(s0, d1); }
        const int row = rbase + tid;
        float2 p; p.x = dm; p.y = sm;
        *(float2*)(bDD + (size_t)row * 64 + chunk * 2) = p;
        bI[(size_t)row * 32 + chunk] = im;
    }

    // ---- one-hot zero slice: nontemporal streaming stores ----
    {
        const int slice = blockIdx.x * 32 + blockIdx.y;   // 0..4095, bijective
        float* oh = out_onehot + (size_t)slice * 16384;
        #pragma unroll
        for (int it = 0; it < 16; ++it)
            nt_store4(oh + it * 1024 + tid * 4, 0.f, 0.f, 0.f, 0.f);
    }
}

// ---------------------------------------------------------------------------
// K1b: resolve — sharp candidate classification (R20, unchanged).
// ---------------------------------------------------------------------------
__global__ __launch_bounds__(128) void resolve_kernel(
        const float* __restrict__ z, const float* __restrict__ W,
        const float* __restrict__ se, const float* __restrict__ sz,
        const float* __restrict__ bDD, const int* __restrict__ bI,
        const float* __restrict__ zt,
        int* __restrict__ idx_ws, float* __restrict__ out_idx,
        float* __restrict__ out_onehot) {
    __shared__ float zr[EDIM];
    __shared__ float rd[128];
    __shared__ int   ri[128];
    __shared__ int   scode[32];
    __shared__ unsigned sfull;
    __shared__ int   sncand;
    const int row = blockIdx.x;
    const int tid = threadIdx.x;

    if (tid < 64) {
        const int c = tid & 31;
        const float2 dd = *(const float2*)(bDD + (size_t)row * 64 + c * 2);
        float g1 = dd.x;
        #pragma unroll
        for (int mask = 16; mask > 0; mask >>= 1)
            g1 = fminf(g1, __shfl_xor(g1, mask));
        const float thr = g1 + MARG;
        const unsigned long long mful = __ballot(dd.y <= thr);
        const unsigned long long mcnd = __ballot(dd.x <= thr && dd.y > thr);
        const unsigned fm = (unsigned)(mful & 0xffffffffu);
        const unsigned cm = (unsigned)(mcnd & 0xffffffffu);
        if (tid < 32 && ((cm >> tid) & 1u)) {
            const int pos = __popc(cm & ((1u << tid) - 1u));
            scode[pos] = bI[(size_t)row * 32 + tid];
        }
        if (tid == 0) { sfull = fm; sncand = __popc(cm); }
    }
    __syncthreads();

    const unsigned fmask = sfull;
    const int ncand = sncand;

    if (fmask == 0u && ncand == 1) {       // unique candidate -> winner
        if (tid == 0) {
            const int ii = scode[0];
            idx_ws[row]  = ii;
            out_idx[row] = (float)ii;
            out_onehot[(size_t)row * N_E + ii] = 1.0f;
        }
        return;
    }

    // exact distances needed: load z row (coalesced via zt when available)
    if (zt) {
        zr[tid]       = zt[(size_t)row * EDIM + tid];
        zr[tid + 128] = zt[(size_t)row * EDIM + tid + 128];
    } else {
        const int b = row >> 13, sp = row & (SPAT - 1);
        zr[tid]       = z[(size_t)b * (EDIM * SPAT) + (size_t)tid * SPAT + sp];
        zr[tid + 128] = z[(size_t)b * (EDIM * SPAT) + (size_t)(tid + 128) * SPAT + sp];
    }
    __syncthreads();

    const float szr = sz[row];
    float best = 3.4e38f; int bi = 0x7fffffff;

    // (a) single-code exact computes (R6-exact serial-k), thread t = cand t
    if (tid < ncand) {
        const int code = scode[tid];
        const float* wr = W + (size_t)code * EDIM;
        float s = 0.f;
        for (int k = 0; k < EDIM; ++k) s += zr[k] * wr[k];   // serial k
        const float q = (szr + se[code]) - 2.0f * s;
        if (q < best || (q == best && code < bi)) { best = q; bi = code; }
    }
    // (b) full-chunk rescans (rare: chunk's 2nd-best within thr)
    unsigned cmask = fmask;
    while (cmask) {
        const int cc = __ffs(cmask) - 1;
        cmask &= cmask - 1;
        const int code = cc * 128 + tid;
        const float* wr = W + (size_t)code * EDIM;
        float s = 0.f;
        for (int k = 0; k < EDIM; ++k) s += zr[k] * wr[k];   // serial k
        const float q = (szr + se[code]) - 2.0f * s;
        if (q < best || (q == best && code < bi)) { best = q; bi = code; }
    }
    rd[tid] = best; ri[tid] = bi;
    __syncthreads();
    for (int off = 64; off > 0; off >>= 1) {
        if (tid < off) {
            const float od = rd[tid + off]; const int oi = ri[tid + off];
            if (od < rd[tid] || (od == rd[tid] && oi < ri[tid])) {
                rd[tid] = od; ri[tid] = oi;
            }
        }
        __syncthreads();
    }
    if (tid == 0) {
        const int ii = ri[0];
        idx_ws[row]  = ii;
        out_idx[row] = (float)ii;
        out_onehot[(size_t)row * N_E + ii] = 1.0f;
    }
}

// ---------------------------------------------------------------------------
// K1c: hist — 16 blocks x 1024 rows, private LDS histogram + global merge.
// ---------------------------------------------------------------------------
__global__ __launch_bounds__(1024) void hist_kernel(const int* __restrict__ idx,
                                                    int* __restrict__ ghist) {
    __shared__ int lh[N_E];
    const int tid = threadIdx.x;
    for (int i = tid; i < N_E; i += 1024) lh[i] = 0;
    __syncthreads();
    atomicAdd(&lh[idx[blockIdx.x * 1024 + tid]], 1);
    __syncthreads();
    for (int c = tid; c < N_E; c += 1024) {
        const int v = lh[c];
        if (v) atomicAdd(&ghist[c], v);
    }
}

// ---------------------------------------------------------------------------
// K2: z_q_out, z_out, loss partials — R6 numerics; nt stores for zq/z_out.
// ---------------------------------------------------------------------------
__global__ __launch_bounds__(256) void outputs_kernel(
        const float* __restrict__ z, const float* __restrict__ W,
        const int* __restrict__ idx,
        float* __restrict__ zq_out, float* __restrict__ z_out,
        double* __restrict__ loss_parts) {
    const int t  = blockIdx.x * 256 + threadIdx.x;
    const float zv = z[t];
    const int sp = t & (SPAT - 1);
    const int c  = (t >> 13) & 255;
    const int b  = t >> 21;
    const int n  = (b << 13) + sp;
    const int id = idx[n];
    const float e    = W[id * EDIM + c];
    const float diff = e - zv;
    nt_store1(zq_out + t, zv + diff);
    nt_store1(z_out + t, zv);

    double ds = (double)(diff * diff);
    #pragma unroll
    for (int off = 32; off > 0; off >>= 1) ds += __shfl_down(ds, off);
    __shared__ double bsum[4];
    const int lane = threadIdx.x & 63, w = threadIdx.x >> 6;
    if (lane == 0) bsum[w] = ds;
    __syncthreads();
    if (threadIdx.x == 0)
        loss_parts[blockIdx.x] = bsum[0] + bsum[1] + bsum[2] + bsum[3];
}

// ---------------------------------------------------------------------------
// K4: perplexity (from ghist, identical c-mapping/order) + loss finalize.
// ---------------------------------------------------------------------------
__global__ __launch_bounds__(1024) void final_kernel(
        const int* __restrict__ ghist, const double* __restrict__ loss_parts,
        float* __restrict__ out_loss, float* __restrict__ out_perp) {
    __shared__ float ps[1024];
    __shared__ double ls[1024];
    const int tid = threadIdx.x;

    float s = 0.f;
    for (int c = tid; c < N_E; c += 1024) {
        const float p = (float)ghist[c] * (1.0f / (float)NROWS);
        s += p * logf(p + 1e-10f);
    }
    double l = 0.0;
    for (int c = tid; c < NLOSSPARTS; c += 1024) l += loss_parts[c];
    ps[tid] = s;
    ls[tid] = l;
    __syncthreads();
    for (int off = 512; off > 0; off >>= 1) {
        if (tid < off) {
            ps[tid] += ps[tid + off];
            ls[tid] += ls[tid + off];
        }
        __syncthreads();
    }
    if (tid == 0) {
        *out_perp = expf(-ps[0]);
        const float m = (float)(ls[0] / (double)ZELEMS);
        *out_loss = m + 0.25f * m;
    }
}

// ---------------------------------------------------------------------------
extern "C" void kernel_launch(void* const* d_in, const int* in_sizes, int n_in,
                              void* d_out, int out_size, void* d_ws, size_t ws_size,
                              hipStream_t stream) {
    const float* z   = (const float*)d_in[0];
    const float* W   = (const float*)d_in[1];
    const float* ema = (const float*)d_in[2];
    float* out = (float*)d_out;

    float* out_loss   = out + OFF_LOSS;
    float* out_zq     = out + OFF_ZQ;
    float* out_perp   = out + OFF_PERP;
    float* out_onehot = out + OFF_ONEHOT;
    float* out_idx    = out + OFF_IDX;
    float* out_z      = out + OFF_ZOUT;
    float* out_ema    = out + OFF_EMA;

    // scratch inside later-overwritten output regions (16B-aligned bases)
    u16*   wh  = (u16*)(out + SCR_WH_F);
    int*   bI  = (int*)(out + SCR_BI_F);
    float* bDD = out + SCR_BDD_F;
    u16*   zh  = (u16*)(out + SCR_ZH_F);

    // workspace
    char* ws = (char*)d_ws;
    float*  se    = (float*)ws;                   // 16 KB
    float*  sz    = (float*)(ws + 16384);         // 64 KB
    int*    idxb  = (int*)  (ws + 81920);         // 64 KB
    double* lossp = (double*)(ws + 147456);       // 128 KB
    int*    ghist = (int*)  (ws + 278528);        // 16 KB
    float*  zt    = (ws_size >= (size_t)ZT_OFF + ZT_BYTES)
                        ? (float*)(ws + ZT_OFF) : (float*)0;  // 16 MB, optional

    prep_all_kernel<<<PB_TOT, 256, 0, stream>>>(W, ema, z, wh, se, out_ema,
                                                zh, sz, ghist, zt);
    argmin_kernel<<<dim3(NROWS / 128, NCHUNK), 256, 0, stream>>>(
        zh, wh, se, sz, bDD, bI, out_onehot);
    resolve_kernel<<<NROWS, 128, 0, stream>>>(z, W, se, sz, bDD, bI, zt,
                                              idxb, out_idx, out_onehot);
    hist_kernel<<<16, 1024, 0, stream>>>(idxb, ghist);
    outputs_kernel<<<ZELEMS / 256, 256, 0, stream>>>(z, W, idxb, out_zq, out_z,
                                                     lossp);
    final_kernel<<<1, 1024, 0, stream>>>(ghist, lossp, out_loss, out_perp);
}